// Round 4
// baseline (562.248 us; speedup 1.0000x reference)
//
#include <hip/hip_runtime.h>

// InfoNCE fused pipeline (round 4):
//   cast   : h,W fp32 -> bf16
//   g1_main: Z = hb @ Wb^T (128x128, BK=32, m97 staging), epilogue quantizes
//            Z to fp8-e4m3 and accumulates norm^2 of the DEQUANTIZED values
//   g2_main: S = Z8[:8192] @ Z8[8192:]^T -- 64x64 tile, K=512 FULLY LDS-RESIDENT
//            in fp8 (A+B strips = 64 KB, 2 blocks/CU), ONE bulk fill + ONE
//            barrier, zero per-iter drains. XOR-swizzled LDS chunks kill the
//            16-way bank conflict on ds_read_b64 frag reads.
//   finalize: loss = mean(log(rowsumexp)) - mean(diag); sim_pos; sim_mean

typedef __attribute__((ext_vector_type(8))) short bf16x8;   // 8 bf16 = 4 VGPRs
typedef __attribute__((ext_vector_type(8))) short short8;
typedef __attribute__((ext_vector_type(4))) float floatx4;  // MFMA C/D frag
typedef unsigned char uchar;

__device__ __forceinline__ unsigned short f2bf(float f) {
    union { float f; unsigned u; } v; v.f = f;
    unsigned r = (v.u + 0x7FFFu + ((v.u >> 16) & 1u)) >> 16;   // RNE
    return (unsigned short)r;
}

// async global->LDS, 16B per lane. LDS dest = wave-uniform base + lane*16.
__device__ __forceinline__ void async_copy16(const void* g, void* l) {
    __builtin_amdgcn_global_load_lds(
        (const __attribute__((address_space(1))) void*)g,
        (__attribute__((address_space(3))) void*)l,
        16, 0, 0);
}

// ---------------------------------------------------------------- cast fp32->bf16
__global__ __launch_bounds__(256) void cast_kernel(
    const float* __restrict__ src, unsigned short* __restrict__ dst, int n)
{
    const int i = (blockIdx.x * 256 + threadIdx.x) * 8;
    if (i + 7 < n) {
        const float4 a = *reinterpret_cast<const float4*>(src + i);
        const float4 b = *reinterpret_cast<const float4*>(src + i + 4);
        short8 o;
        o[0] = (short)f2bf(a.x); o[1] = (short)f2bf(a.y);
        o[2] = (short)f2bf(a.z); o[3] = (short)f2bf(a.w);
        o[4] = (short)f2bf(b.x); o[5] = (short)f2bf(b.y);
        o[6] = (short)f2bf(b.z); o[7] = (short)f2bf(b.w);
        *reinterpret_cast<short8*>(dst + i) = o;
    }
}

// ---------------------------------------------------------------- g1_main
// Z8[16384,512] = fp8(hb[16384,2048] @ Wb[512,2048]^T), + row norm^2 of the
// dequantized fp8 values (so g2's cosine is exactly of the quantized vectors).
// 128x128 tile, BK=32, m97 global_load_lds staging (round-2 structure).
__global__ __launch_bounds__(256) void g1_main(
    const unsigned short* __restrict__ hb, const unsigned short* __restrict__ Wb,
    uchar* __restrict__ Z8, float* __restrict__ norm2)
{
    __shared__ __align__(16) unsigned short As[128 * 32];  // unpadded: global_load_lds layout
    __shared__ __align__(16) unsigned short Bs[128 * 32];

    const int bn = blockIdx.x;        // 0..3   (N=512)
    const int bm = blockIdx.y;        // 0..127 (M=16384)
    const int t = threadIdx.x;
    const int wave = t >> 6, lane = t & 63;
    const int wm = wave & 1, wn = wave >> 1;
    const int quad = lane >> 4, l15 = lane & 15;

    floatx4 acc[4][4];
    #pragma unroll
    for (int i = 0; i < 4; i++)
        #pragma unroll
        for (int j = 0; j < 4; j++) acc[i][j] = {0.f, 0.f, 0.f, 0.f};

    const int srow = lane >> 2, skcol = (lane & 3) * 8;
    unsigned short* lA0 = &As[(wave * 32 +  0) * 32];
    unsigned short* lA1 = &As[(wave * 32 + 16) * 32];
    unsigned short* lB0 = &Bs[(wave * 32 +  0) * 32];
    unsigned short* lB1 = &Bs[(wave * 32 + 16) * 32];
    const unsigned short* gA0 = hb + (size_t)(bm * 128 + wave * 32 + srow) * 2048 + skcol;
    const unsigned short* gA1 = gA0 + (size_t)16 * 2048;
    const unsigned short* gB0 = Wb + (size_t)(bn * 128 + wave * 32 + srow) * 2048 + skcol;
    const unsigned short* gB1 = gB0 + (size_t)16 * 2048;

    for (int k0 = 0; k0 < 2048; k0 += 32) {
        async_copy16(gA0 + k0, lA0);
        async_copy16(gA1 + k0, lA1);
        async_copy16(gB0 + k0, lB0);
        async_copy16(gB1 + k0, lB1);
        __syncthreads();
        bf16x8 af[4], bfr[4];
        #pragma unroll
        for (int i = 0; i < 4; i++)
            af[i] = *reinterpret_cast<const bf16x8*>(&As[(wm * 64 + i * 16 + l15) * 32 + quad * 8]);
        #pragma unroll
        for (int j = 0; j < 4; j++)
            bfr[j] = *reinterpret_cast<const bf16x8*>(&Bs[(wn * 64 + j * 16 + l15) * 32 + quad * 8]);
        #pragma unroll
        for (int i = 0; i < 4; i++)
            #pragma unroll
            for (int j = 0; j < 4; j++)
                acc[i][j] = __builtin_amdgcn_mfma_f32_16x16x32_bf16(af[i], bfr[j], acc[i][j], 0, 0, 0);
        __syncthreads();
    }

    // Epilogue: quantize to fp8-e4m3, store, norm^2 from dequantized values.
    // C/D map: col=l15, row=quad*4+r
    #pragma unroll
    for (int i = 0; i < 4; i++) {
        #pragma unroll
        for (int r = 0; r < 4; r++) {
            const int row_g = bm * 128 + wm * 64 + i * 16 + quad * 4 + r;
            const int pk01 = __builtin_amdgcn_cvt_pk_fp8_f32(acc[i][0][r], acc[i][1][r], 0, 0);
            const int pk23 = __builtin_amdgcn_cvt_pk_fp8_f32(acc[i][2][r], acc[i][3][r], 0, 0);
            const size_t rbase = (size_t)row_g * 512 + bn * 128 + wn * 64 + l15;
            Z8[rbase +  0] = (uchar)(pk01 & 0xff);
            Z8[rbase + 16] = (uchar)((pk01 >> 8) & 0xff);
            Z8[rbase + 32] = (uchar)(pk23 & 0xff);
            Z8[rbase + 48] = (uchar)((pk23 >> 8) & 0xff);
            const float q0 = __builtin_amdgcn_cvt_f32_fp8(pk01, 0);
            const float q1 = __builtin_amdgcn_cvt_f32_fp8(pk01, 1);
            const float q2 = __builtin_amdgcn_cvt_f32_fp8(pk23, 0);
            const float q3 = __builtin_amdgcn_cvt_f32_fp8(pk23, 1);
            float p = q0 * q0 + q1 * q1 + q2 * q2 + q3 * q3;
            p += __shfl_xor(p, 1, 16);
            p += __shfl_xor(p, 2, 16);
            p += __shfl_xor(p, 4, 16);
            p += __shfl_xor(p, 8, 16);
            if (l15 == 0) atomicAdd(&norm2[row_g], p);
        }
    }
}

// ---------------------------------------------------------------- g1_slow (fallback, fp32 in)
__global__ __launch_bounds__(256) void g1_slow(
    const float* __restrict__ h, const float* __restrict__ W,
    uchar* __restrict__ Z8, float* __restrict__ norm2)
{
    __shared__ __align__(16) unsigned short As[128][40];
    __shared__ __align__(16) unsigned short Bs[128][40];

    const int bn = blockIdx.x, bm = blockIdx.y;
    const int t = threadIdx.x;
    const int wave = t >> 6, lane = t & 63;
    const int wm = wave & 1, wn = wave >> 1;
    const int quad = lane >> 4, l15 = lane & 15;

    floatx4 acc[4][4];
    #pragma unroll
    for (int i = 0; i < 4; i++)
        #pragma unroll
        for (int j = 0; j < 4; j++) acc[i][j] = {0.f, 0.f, 0.f, 0.f};

    const int lrow = t >> 1, lhalf = t & 1;
    const float* ga = h + (size_t)(bm * 128 + lrow) * 2048 + lhalf * 16;
    const float* gb = W + (size_t)(bn * 128 + lrow) * 2048 + lhalf * 16;

    for (int k0 = 0; k0 < 2048; k0 += 32) {
        #pragma unroll
        for (int c = 0; c < 4; c++) {
            const float4 va = *reinterpret_cast<const float4*>(ga + k0 + c * 4);
            const float4 vb = *reinterpret_cast<const float4*>(gb + k0 + c * 4);
            ushort4 ua = make_ushort4(f2bf(va.x), f2bf(va.y), f2bf(va.z), f2bf(va.w));
            ushort4 ub = make_ushort4(f2bf(vb.x), f2bf(vb.y), f2bf(vb.z), f2bf(vb.w));
            *reinterpret_cast<ushort4*>(&As[lrow][lhalf * 16 + c * 4]) = ua;
            *reinterpret_cast<ushort4*>(&Bs[lrow][lhalf * 16 + c * 4]) = ub;
        }
        __syncthreads();
        bf16x8 af[4], bfr[4];
        #pragma unroll
        for (int i = 0; i < 4; i++)
            af[i] = *reinterpret_cast<const bf16x8*>(&As[wm * 64 + i * 16 + l15][quad * 8]);
        #pragma unroll
        for (int j = 0; j < 4; j++)
            bfr[j] = *reinterpret_cast<const bf16x8*>(&Bs[wn * 64 + j * 16 + l15][quad * 8]);
        #pragma unroll
        for (int i = 0; i < 4; i++)
            #pragma unroll
            for (int j = 0; j < 4; j++)
                acc[i][j] = __builtin_amdgcn_mfma_f32_16x16x32_bf16(af[i], bfr[j], acc[i][j], 0, 0, 0);
        __syncthreads();
    }

    #pragma unroll
    for (int i = 0; i < 4; i++) {
        #pragma unroll
        for (int r = 0; r < 4; r++) {
            const int row_g = bm * 128 + wm * 64 + i * 16 + quad * 4 + r;
            const int pk01 = __builtin_amdgcn_cvt_pk_fp8_f32(acc[i][0][r], acc[i][1][r], 0, 0);
            const int pk23 = __builtin_amdgcn_cvt_pk_fp8_f32(acc[i][2][r], acc[i][3][r], 0, 0);
            const size_t rbase = (size_t)row_g * 512 + bn * 128 + wn * 64 + l15;
            Z8[rbase +  0] = (uchar)(pk01 & 0xff);
            Z8[rbase + 16] = (uchar)((pk01 >> 8) & 0xff);
            Z8[rbase + 32] = (uchar)(pk23 & 0xff);
            Z8[rbase + 48] = (uchar)((pk23 >> 8) & 0xff);
            const float q0 = __builtin_amdgcn_cvt_f32_fp8(pk01, 0);
            const float q1 = __builtin_amdgcn_cvt_f32_fp8(pk01, 1);
            const float q2 = __builtin_amdgcn_cvt_f32_fp8(pk23, 0);
            const float q3 = __builtin_amdgcn_cvt_f32_fp8(pk23, 1);
            float p = q0 * q0 + q1 * q1 + q2 * q2 + q3 * q3;
            p += __shfl_xor(p, 1, 16);
            p += __shfl_xor(p, 2, 16);
            p += __shfl_xor(p, 4, 16);
            p += __shfl_xor(p, 8, 16);
            if (l15 == 0) atomicAdd(&norm2[row_g], p);
        }
    }
}

// ---------------------------------------------------------------- g2_main
// S = Z8[:8192] @ Z8[8192:]^T, fp8 MFMA, 64x64 tile, K=512 fully LDS-resident.
// One bulk fill (XOR-swizzled 16B chunks), one barrier, then pure compute.
__global__ __launch_bounds__(256, 2) void g2_main(
    const uchar* __restrict__ Z8, const float* __restrict__ norm2,
    float* __restrict__ rowse, float* __restrict__ bsum, float* __restrict__ bdiag)
{
    __shared__ __align__(16) uchar As[64 * 512];   // 32 KB: A strip, rows bm*64..+64
    __shared__ __align__(16) uchar Bs[64 * 512];   // 32 KB: B strip (context)
    __shared__ float red[8];

    const int bn = blockIdx.x;        // 0..127
    const int bm = blockIdx.y;        // 0..127
    const int t = threadIdx.x;
    const int wave = t >> 6, lane = t & 63;
    const int wm = wave & 1, wn = wave >> 1;       // wave tile 32x32
    const int quad = lane >> 4, l15 = lane & 15;

    const uchar* gA = Z8 + (size_t)(bm * 64) * 512;
    const uchar* gB = Z8 + (size_t)(8192 + bn * 64) * 512;

    // Bulk fill: wave fills 8 KB of each strip (8 instrs), 1 KB/instr = 2 rows.
    // LDS slot s of row m holds global 16B chunk (s ^ (m&31))  -> frag reads
    // land on spread banks instead of a 16-way conflict.
    {
        const int sub = lane >> 5;     // row within the 1KB chunk
        const int slot = lane & 31;    // 16B slot within row
        #pragma unroll
        for (int i = 0; i < 8; i++) {
            const int m = wave * 16 + 2 * i + sub;
            const int goff = m * 512 + ((slot ^ (m & 31)) << 4);
            async_copy16(gA + goff, &As[wave * 8192 + i * 1024]);
            async_copy16(gB + goff, &Bs[wave * 8192 + i * 1024]);
        }
    }
    __syncthreads();   // drains vmcnt(0) then barrier — the ONLY drain

    floatx4 acc[2][2];
    acc[0][0] = {0.f,0.f,0.f,0.f}; acc[0][1] = {0.f,0.f,0.f,0.f};
    acc[1][0] = {0.f,0.f,0.f,0.f}; acc[1][1] = {0.f,0.f,0.f,0.f};

    // per-lane frag address components (fp8 16x16x32: lane l15 = row, k = quad*8+j)
    const int m0 = wm * 32 + l15, m1 = m0 + 16;
    const int n0 = wn * 32 + l15, n1 = n0 + 16;
    const int off8 = (quad & 1) * 8;
    const int mb0 = m0 * 512 + off8, mb1 = m1 * 512 + off8;
    const int nb0 = n0 * 512 + off8, nb1 = n1 * 512 + off8;
    const int ms0 = m0 & 31, ms1 = m1 & 31;
    const int ns0 = n0 & 31, ns1 = n1 & 31;
    const int chq = quad >> 1;

    #pragma unroll
    for (int ks = 0; ks < 16; ks++) {
        const int ch = 2 * ks + chq;   // 16B chunk index of this frag's k-range
        const long a0 = *reinterpret_cast<const long*>(As + mb0 + ((ch ^ ms0) << 4));
        const long a1 = *reinterpret_cast<const long*>(As + mb1 + ((ch ^ ms1) << 4));
        const long b0 = *reinterpret_cast<const long*>(Bs + nb0 + ((ch ^ ns0) << 4));
        const long b1 = *reinterpret_cast<const long*>(Bs + nb1 + ((ch ^ ns1) << 4));
        acc[0][0] = __builtin_amdgcn_mfma_f32_16x16x32_fp8_fp8(a0, b0, acc[0][0], 0, 0, 0);
        acc[0][1] = __builtin_amdgcn_mfma_f32_16x16x32_fp8_fp8(a0, b1, acc[0][1], 0, 0, 0);
        acc[1][0] = __builtin_amdgcn_mfma_f32_16x16x32_fp8_fp8(a1, b0, acc[1][0], 0, 0, 0);
        acc[1][1] = __builtin_amdgcn_mfma_f32_16x16x32_fp8_fp8(a1, b1, acc[1][1], 0, 0, 0);
    }

    // Fused epilogue: sim = dot * rsqrt(n2_i) * rsqrt(n2_j) / TEMP
    float rc[2];
    #pragma unroll
    for (int j = 0; j < 2; j++)
        rc[j] = rsqrtf(fmaxf(norm2[8192 + bn * 64 + wn * 32 + j * 16 + l15], 1e-30f));

    float s_total = 0.f, s_diag = 0.f;
    #pragma unroll
    for (int i = 0; i < 2; i++) {
        #pragma unroll
        for (int r = 0; r < 4; r++) {
            const int row_g = bm * 64 + wm * 32 + i * 16 + quad * 4 + r;
            const float rz = rsqrtf(fmaxf(norm2[row_g], 1e-30f));
            float rowexp = 0.f;
            #pragma unroll
            for (int j = 0; j < 2; j++) {
                const int col_g = bn * 64 + wn * 32 + j * 16 + l15;
                const float sim = acc[i][j][r] * rz * rc[j] * 10.0f;  // 1/TEMP
                s_total += sim;
                rowexp += __expf(sim);
                if (col_g == row_g) s_diag += sim;
            }
            rowexp += __shfl_xor(rowexp, 1, 16);
            rowexp += __shfl_xor(rowexp, 2, 16);
            rowexp += __shfl_xor(rowexp, 4, 16);
            rowexp += __shfl_xor(rowexp, 8, 16);
            if (l15 == 0) atomicAdd(&rowse[row_g], rowexp);
        }
    }
    #pragma unroll
    for (int off = 32; off; off >>= 1) {
        s_total += __shfl_xor(s_total, off, 64);
        s_diag  += __shfl_xor(s_diag, off, 64);
    }
    if (lane == 0) { red[wave] = s_total; red[4 + wave] = s_diag; }
    __syncthreads();
    if (t == 0) {
        bsum[bm * 128 + bn]  = red[0] + red[1] + red[2] + red[3];
        bdiag[bm * 128 + bn] = red[4] + red[5] + red[6] + red[7];
    }
}

// ---------------------------------------------------------------- finalize
__global__ __launch_bounds__(256) void finalize_kernel(
    const float* __restrict__ rowse, const float* __restrict__ bsum,
    const float* __restrict__ bdiag, float* __restrict__ out)
{
    float a = 0.f, b = 0.f, c = 0.f;
    for (int i = threadIdx.x; i < 8192; i += 256) a += logf(rowse[i]);
    for (int i = threadIdx.x; i < 16384; i += 256) { b += bsum[i]; c += bdiag[i]; }
    #pragma unroll
    for (int off = 32; off; off >>= 1) {
        a += __shfl_xor(a, off, 64);
        b += __shfl_xor(b, off, 64);
        c += __shfl_xor(c, off, 64);
    }
    __shared__ float ra[4], rb[4], rc[4];
    const int wave = threadIdx.x >> 6, lane = threadIdx.x & 63;
    if (lane == 0) { ra[wave] = a; rb[wave] = b; rc[wave] = c; }
    __syncthreads();
    if (threadIdx.x == 0) {
        const float A = ra[0] + ra[1] + ra[2] + ra[3];
        const float B = rb[0] + rb[1] + rb[2] + rb[3];
        const float C = rc[0] + rc[1] + rc[2] + rc[3];
        const float diag_mean = C / 8192.f;
        out[0] = A / 8192.f - diag_mean;            // loss
        out[1] = diag_mean;                         // sim_pos
        out[2] = B / (8192.f * 8192.f);             // sim_mean
    }
}

// ---------------------------------------------------------------- launch
extern "C" void kernel_launch(void* const* d_in, const int* in_sizes, int n_in,
                              void* d_out, int out_size, void* d_ws, size_t ws_size,
                              hipStream_t stream) {
    const float* h = (const float*)d_in[0];   // [16384, 2048]
    const float* W = (const float*)d_in[1];   // [512, 2048]
    float* out = (float*)d_out;               // [3]

    char* ws = (char*)d_ws;
    float* norm2 = (float*)(ws);                            // 16384 f @ 0
    float* rowse = (float*)(ws + 65536);                    //  8192 f
    float* bsum  = (float*)(ws + 98304);                    // 16384 f
    float* bdiag = (float*)(ws + 163840);                   // 16384 f
    uchar* Z8    = (uchar*)(ws + 229376);                   // 16384x512 fp8 (8.39 MB)
    unsigned short* Wb = (unsigned short*)(ws + 8617984);   // 512x2048 bf16 (2 MB)
    unsigned short* hb = (unsigned short*)(ws + 10715136);  // 16384x2048 bf16 (67.1 MB)
    const size_t NEED_FAST = 10715136ull + 67108864ull;     // ~77.8 MB

    hipMemsetAsync(ws, 0, 229376, stream);    // zero atomic accumulators

    if (ws_size >= NEED_FAST) {
        const int nh = 16384 * 2048, nw = 512 * 2048;
        hipLaunchKernelGGL(cast_kernel, dim3(nh / 2048), dim3(256), 0, stream, h, hb, nh);
        hipLaunchKernelGGL(cast_kernel, dim3(nw / 2048), dim3(256), 0, stream, W, Wb, nw);
        hipLaunchKernelGGL(g1_main, dim3(4, 128), dim3(256), 0, stream, hb, Wb, Z8, norm2);
    } else {
        hipLaunchKernelGGL(g1_slow, dim3(4, 128), dim3(256), 0, stream, h, W, Z8, norm2);
    }
    hipLaunchKernelGGL(g2_main, dim3(128, 128), dim3(256), 0, stream, Z8, norm2, rowse, bsum, bdiag);
    hipLaunchKernelGGL(finalize_kernel, dim3(1), dim3(256), 0, stream, rowse, bsum, bdiag, out);
}

// Round 5
// 550.635 us; speedup vs baseline: 1.0211x; 1.0211x over previous
//
#include <hip/hip_runtime.h>

// InfoNCE fused pipeline (round 5):
//   cast   : h,W fp32 -> bf16
//   g1_main: Z = hb @ Wb^T (128x128, BK=32, m97 staging), epilogue quantizes
//            Z to fp8-e4m3 + norm^2 of the DEQUANTIZED values  [r4, proven]
//   g2_main: S = Z8[:8192] @ Z8[8192:]^T via MX-scaled fp8 MFMA 16x16x128
//            (scales pinned to 1.0), 128x128 tile, BK=128 -> 4 K-iters,
//            XOR-swizzled LDS (r4-verified: conflicts=0), fused epilogue.
//   finalize: loss = mean(log(rowsumexp)) - mean(diag); sim_pos; sim_mean

typedef __attribute__((ext_vector_type(8))) short bf16x8;   // 8 bf16 = 4 VGPRs
typedef __attribute__((ext_vector_type(8))) short short8;
typedef __attribute__((ext_vector_type(4))) float floatx4;  // MFMA C/D frag
typedef __attribute__((ext_vector_type(8))) int   intx8;    // f8f6f4 A/B frag (32B)
typedef __attribute__((ext_vector_type(4))) int   intx4;
typedef unsigned char uchar;

__device__ __forceinline__ unsigned short f2bf(float f) {
    union { float f; unsigned u; } v; v.f = f;
    unsigned r = (v.u + 0x7FFFu + ((v.u >> 16) & 1u)) >> 16;   // RNE
    return (unsigned short)r;
}

// async global->LDS, 16B per lane. LDS dest = wave-uniform base + lane*16.
__device__ __forceinline__ void async_copy16(const void* g, void* l) {
    __builtin_amdgcn_global_load_lds(
        (const __attribute__((address_space(1))) void*)g,
        (__attribute__((address_space(3))) void*)l,
        16, 0, 0);
}

// ---------------------------------------------------------------- cast fp32->bf16
__global__ __launch_bounds__(256) void cast_kernel(
    const float* __restrict__ src, unsigned short* __restrict__ dst, int n)
{
    const int i = (blockIdx.x * 256 + threadIdx.x) * 8;
    if (i + 7 < n) {
        const float4 a = *reinterpret_cast<const float4*>(src + i);
        const float4 b = *reinterpret_cast<const float4*>(src + i + 4);
        short8 o;
        o[0] = (short)f2bf(a.x); o[1] = (short)f2bf(a.y);
        o[2] = (short)f2bf(a.z); o[3] = (short)f2bf(a.w);
        o[4] = (short)f2bf(b.x); o[5] = (short)f2bf(b.y);
        o[6] = (short)f2bf(b.z); o[7] = (short)f2bf(b.w);
        *reinterpret_cast<short8*>(dst + i) = o;
    }
}

// ---------------------------------------------------------------- g1_main (r4, proven)
__global__ __launch_bounds__(256) void g1_main(
    const unsigned short* __restrict__ hb, const unsigned short* __restrict__ Wb,
    uchar* __restrict__ Z8, float* __restrict__ norm2)
{
    __shared__ __align__(16) unsigned short As[128 * 32];
    __shared__ __align__(16) unsigned short Bs[128 * 32];

    const int bn = blockIdx.x;        // 0..3   (N=512)
    const int bm = blockIdx.y;        // 0..127 (M=16384)
    const int t = threadIdx.x;
    const int wave = t >> 6, lane = t & 63;
    const int wm = wave & 1, wn = wave >> 1;
    const int quad = lane >> 4, l15 = lane & 15;

    floatx4 acc[4][4];
    #pragma unroll
    for (int i = 0; i < 4; i++)
        #pragma unroll
        for (int j = 0; j < 4; j++) acc[i][j] = {0.f, 0.f, 0.f, 0.f};

    const int srow = lane >> 2, skcol = (lane & 3) * 8;
    unsigned short* lA0 = &As[(wave * 32 +  0) * 32];
    unsigned short* lA1 = &As[(wave * 32 + 16) * 32];
    unsigned short* lB0 = &Bs[(wave * 32 +  0) * 32];
    unsigned short* lB1 = &Bs[(wave * 32 + 16) * 32];
    const unsigned short* gA0 = hb + (size_t)(bm * 128 + wave * 32 + srow) * 2048 + skcol;
    const unsigned short* gA1 = gA0 + (size_t)16 * 2048;
    const unsigned short* gB0 = Wb + (size_t)(bn * 128 + wave * 32 + srow) * 2048 + skcol;
    const unsigned short* gB1 = gB0 + (size_t)16 * 2048;

    for (int k0 = 0; k0 < 2048; k0 += 32) {
        async_copy16(gA0 + k0, lA0);
        async_copy16(gA1 + k0, lA1);
        async_copy16(gB0 + k0, lB0);
        async_copy16(gB1 + k0, lB1);
        __syncthreads();
        bf16x8 af[4], bfr[4];
        #pragma unroll
        for (int i = 0; i < 4; i++)
            af[i] = *reinterpret_cast<const bf16x8*>(&As[(wm * 64 + i * 16 + l15) * 32 + quad * 8]);
        #pragma unroll
        for (int j = 0; j < 4; j++)
            bfr[j] = *reinterpret_cast<const bf16x8*>(&Bs[(wn * 64 + j * 16 + l15) * 32 + quad * 8]);
        #pragma unroll
        for (int i = 0; i < 4; i++)
            #pragma unroll
            for (int j = 0; j < 4; j++)
                acc[i][j] = __builtin_amdgcn_mfma_f32_16x16x32_bf16(af[i], bfr[j], acc[i][j], 0, 0, 0);
        __syncthreads();
    }

    #pragma unroll
    for (int i = 0; i < 4; i++) {
        #pragma unroll
        for (int r = 0; r < 4; r++) {
            const int row_g = bm * 128 + wm * 64 + i * 16 + quad * 4 + r;
            const int pk01 = __builtin_amdgcn_cvt_pk_fp8_f32(acc[i][0][r], acc[i][1][r], 0, 0);
            const int pk23 = __builtin_amdgcn_cvt_pk_fp8_f32(acc[i][2][r], acc[i][3][r], 0, 0);
            const size_t rbase = (size_t)row_g * 512 + bn * 128 + wn * 64 + l15;
            Z8[rbase +  0] = (uchar)(pk01 & 0xff);
            Z8[rbase + 16] = (uchar)((pk01 >> 8) & 0xff);
            Z8[rbase + 32] = (uchar)(pk23 & 0xff);
            Z8[rbase + 48] = (uchar)((pk23 >> 8) & 0xff);
            const float q0 = __builtin_amdgcn_cvt_f32_fp8(pk01, 0);
            const float q1 = __builtin_amdgcn_cvt_f32_fp8(pk01, 1);
            const float q2 = __builtin_amdgcn_cvt_f32_fp8(pk23, 0);
            const float q3 = __builtin_amdgcn_cvt_f32_fp8(pk23, 1);
            float p = q0 * q0 + q1 * q1 + q2 * q2 + q3 * q3;
            p += __shfl_xor(p, 1, 16);
            p += __shfl_xor(p, 2, 16);
            p += __shfl_xor(p, 4, 16);
            p += __shfl_xor(p, 8, 16);
            if (l15 == 0) atomicAdd(&norm2[row_g], p);
        }
    }
}

// ---------------------------------------------------------------- g1_slow (fallback, fp32 in)
__global__ __launch_bounds__(256) void g1_slow(
    const float* __restrict__ h, const float* __restrict__ W,
    uchar* __restrict__ Z8, float* __restrict__ norm2)
{
    __shared__ __align__(16) unsigned short As[128][40];
    __shared__ __align__(16) unsigned short Bs[128][40];

    const int bn = blockIdx.x, bm = blockIdx.y;
    const int t = threadIdx.x;
    const int wave = t >> 6, lane = t & 63;
    const int wm = wave & 1, wn = wave >> 1;
    const int quad = lane >> 4, l15 = lane & 15;

    floatx4 acc[4][4];
    #pragma unroll
    for (int i = 0; i < 4; i++)
        #pragma unroll
        for (int j = 0; j < 4; j++) acc[i][j] = {0.f, 0.f, 0.f, 0.f};

    const int lrow = t >> 1, lhalf = t & 1;
    const float* ga = h + (size_t)(bm * 128 + lrow) * 2048 + lhalf * 16;
    const float* gb = W + (size_t)(bn * 128 + lrow) * 2048 + lhalf * 16;

    for (int k0 = 0; k0 < 2048; k0 += 32) {
        #pragma unroll
        for (int c = 0; c < 4; c++) {
            const float4 va = *reinterpret_cast<const float4*>(ga + k0 + c * 4);
            const float4 vb = *reinterpret_cast<const float4*>(gb + k0 + c * 4);
            ushort4 ua = make_ushort4(f2bf(va.x), f2bf(va.y), f2bf(va.z), f2bf(va.w));
            ushort4 ub = make_ushort4(f2bf(vb.x), f2bf(vb.y), f2bf(vb.z), f2bf(vb.w));
            *reinterpret_cast<ushort4*>(&As[lrow][lhalf * 16 + c * 4]) = ua;
            *reinterpret_cast<ushort4*>(&Bs[lrow][lhalf * 16 + c * 4]) = ub;
        }
        __syncthreads();
        bf16x8 af[4], bfr[4];
        #pragma unroll
        for (int i = 0; i < 4; i++)
            af[i] = *reinterpret_cast<const bf16x8*>(&As[wm * 64 + i * 16 + l15][quad * 8]);
        #pragma unroll
        for (int j = 0; j < 4; j++)
            bfr[j] = *reinterpret_cast<const bf16x8*>(&Bs[wn * 64 + j * 16 + l15][quad * 8]);
        #pragma unroll
        for (int i = 0; i < 4; i++)
            #pragma unroll
            for (int j = 0; j < 4; j++)
                acc[i][j] = __builtin_amdgcn_mfma_f32_16x16x32_bf16(af[i], bfr[j], acc[i][j], 0, 0, 0);
        __syncthreads();
    }

    #pragma unroll
    for (int i = 0; i < 4; i++) {
        #pragma unroll
        for (int r = 0; r < 4; r++) {
            const int row_g = bm * 128 + wm * 64 + i * 16 + quad * 4 + r;
            const int pk01 = __builtin_amdgcn_cvt_pk_fp8_f32(acc[i][0][r], acc[i][1][r], 0, 0);
            const int pk23 = __builtin_amdgcn_cvt_pk_fp8_f32(acc[i][2][r], acc[i][3][r], 0, 0);
            const size_t rbase = (size_t)row_g * 512 + bn * 128 + wn * 64 + l15;
            Z8[rbase +  0] = (uchar)(pk01 & 0xff);
            Z8[rbase + 16] = (uchar)((pk01 >> 8) & 0xff);
            Z8[rbase + 32] = (uchar)(pk23 & 0xff);
            Z8[rbase + 48] = (uchar)((pk23 >> 8) & 0xff);
            const float q0 = __builtin_amdgcn_cvt_f32_fp8(pk01, 0);
            const float q1 = __builtin_amdgcn_cvt_f32_fp8(pk01, 1);
            const float q2 = __builtin_amdgcn_cvt_f32_fp8(pk23, 0);
            const float q3 = __builtin_amdgcn_cvt_f32_fp8(pk23, 1);
            float p = q0 * q0 + q1 * q1 + q2 * q2 + q3 * q3;
            p += __shfl_xor(p, 1, 16);
            p += __shfl_xor(p, 2, 16);
            p += __shfl_xor(p, 4, 16);
            p += __shfl_xor(p, 8, 16);
            if (l15 == 0) atomicAdd(&norm2[row_g], p);
        }
    }
}

// ---------------------------------------------------------------- g2_main
// S = Z8[:8192] @ Z8[8192:]^T via MX fp8 MFMA 16x16x128 (scale=1.0).
// 128x128 tile, BK=128 (32 KB LDS), 4 K-iters. LDS 16B chunk s of row m
// holds global chunk s^(m&7): frag-read banks = 4*slot, (m,m+8) pair
// -> 2-way = free [r4-verified swizzle, conflicts=0].
__global__ __launch_bounds__(256, 3) void g2_main(
    const uchar* __restrict__ Z8, const float* __restrict__ norm2,
    float* __restrict__ rowse, float* __restrict__ bsum, float* __restrict__ bdiag)
{
    __shared__ __align__(16) uchar As[128 * 128];   // 16 KB
    __shared__ __align__(16) uchar Bs[128 * 128];   // 16 KB
    __shared__ float red[8];

    const int bn = blockIdx.x;        // 0..63
    const int bm = blockIdx.y;        // 0..63
    const int t = threadIdx.x;
    const int wave = t >> 6, lane = t & 63;
    const int wm = wave & 1, wn = wave >> 1;       // 64x64 quadrant per wave
    const int quad = lane >> 4, l15 = lane & 15;

    const uchar* gA = Z8 + (size_t)(bm * 128) * 512;
    const uchar* gB = Z8 + (size_t)(8192 + bn * 128) * 512;

    floatx4 acc[4][4];
    #pragma unroll
    for (int i = 0; i < 4; i++)
        #pragma unroll
        for (int j = 0; j < 4; j++) acc[i][j] = {0.f, 0.f, 0.f, 0.f};

    // fill map: one instr covers 8 rows x 128 B; lane l -> row l>>3, slot l&7
    const int frow = lane >> 3, fslot = lane & 7;

    for (int ks = 0; ks < 4; ks++) {
        const int k0 = ks * 128;
        #pragma unroll
        for (int i = 0; i < 4; i++) {
            const int rT = wave * 32 + i * 8 + frow;                 // tile row
            const int src = rT * 512 + k0 + ((fslot ^ (rT & 7)) << 4);
            async_copy16(gA + src, &As[(wave * 32 + i * 8) * 128]);
            async_copy16(gB + src, &Bs[(wave * 32 + i * 8) * 128]);
        }
        __syncthreads();

        intx8 af[4], bf[4];
        #pragma unroll
        for (int i = 0; i < 4; i++) {
            const int m = wm * 64 + i * 16 + l15;
            const int c0 = (2 * quad) ^ (m & 7), c1 = (2 * quad + 1) ^ (m & 7);
            const intx4 lo = *reinterpret_cast<const intx4*>(&As[m * 128 + (c0 << 4)]);
            const intx4 hi = *reinterpret_cast<const intx4*>(&As[m * 128 + (c1 << 4)]);
            af[i][0] = lo[0]; af[i][1] = lo[1]; af[i][2] = lo[2]; af[i][3] = lo[3];
            af[i][4] = hi[0]; af[i][5] = hi[1]; af[i][6] = hi[2]; af[i][7] = hi[3];
        }
        #pragma unroll
        for (int j = 0; j < 4; j++) {
            const int n = wn * 64 + j * 16 + l15;
            const int c0 = (2 * quad) ^ (n & 7), c1 = (2 * quad + 1) ^ (n & 7);
            const intx4 lo = *reinterpret_cast<const intx4*>(&Bs[n * 128 + (c0 << 4)]);
            const intx4 hi = *reinterpret_cast<const intx4*>(&Bs[n * 128 + (c1 << 4)]);
            bf[j][0] = lo[0]; bf[j][1] = lo[1]; bf[j][2] = lo[2]; bf[j][3] = lo[3];
            bf[j][4] = hi[0]; bf[j][5] = hi[1]; bf[j][6] = hi[2]; bf[j][7] = hi[3];
        }
        #pragma unroll
        for (int i = 0; i < 4; i++)
            #pragma unroll
            for (int j = 0; j < 4; j++)
                acc[i][j] = __builtin_amdgcn_mfma_scale_f32_16x16x128_f8f6f4(
                    af[i], bf[j], acc[i][j], 0, 0, 0, 127, 0, 127);  // fp8/fp8, scale=1.0
        __syncthreads();
    }

    // Fused epilogue: sim = dot * rsqrt(n2_i) * rsqrt(n2_j) / TEMP
    float rc4[4];
    #pragma unroll
    for (int j = 0; j < 4; j++)
        rc4[j] = rsqrtf(fmaxf(norm2[8192 + bn * 128 + wn * 64 + j * 16 + l15], 1e-30f));

    float s_total = 0.f, s_diag = 0.f;
    #pragma unroll
    for (int i = 0; i < 4; i++) {
        #pragma unroll
        for (int r = 0; r < 4; r++) {
            const int row_g = bm * 128 + wm * 64 + i * 16 + quad * 4 + r;
            const float rz = rsqrtf(fmaxf(norm2[row_g], 1e-30f));
            float rowexp = 0.f;
            #pragma unroll
            for (int j = 0; j < 4; j++) {
                const int col_g = bn * 128 + wn * 64 + j * 16 + l15;
                const float sim = acc[i][j][r] * rz * rc4[j] * 10.0f;  // 1/TEMP
                s_total += sim;
                rowexp += __expf(sim);
                if (col_g == row_g) s_diag += sim;
            }
            rowexp += __shfl_xor(rowexp, 1, 16);
            rowexp += __shfl_xor(rowexp, 2, 16);
            rowexp += __shfl_xor(rowexp, 4, 16);
            rowexp += __shfl_xor(rowexp, 8, 16);
            if (l15 == 0) atomicAdd(&rowse[row_g], rowexp);
        }
    }
    #pragma unroll
    for (int off = 32; off; off >>= 1) {
        s_total += __shfl_xor(s_total, off, 64);
        s_diag  += __shfl_xor(s_diag, off, 64);
    }
    if (lane == 0) { red[wave] = s_total; red[4 + wave] = s_diag; }
    __syncthreads();
    if (t == 0) {
        bsum[bm * 64 + bn]  = red[0] + red[1] + red[2] + red[3];
        bdiag[bm * 64 + bn] = red[4] + red[5] + red[6] + red[7];
    }
}

// ---------------------------------------------------------------- finalize
__global__ __launch_bounds__(256) void finalize_kernel(
    const float* __restrict__ rowse, const float* __restrict__ bsum,
    const float* __restrict__ bdiag, float* __restrict__ out)
{
    float a = 0.f, b = 0.f, c = 0.f;
    for (int i = threadIdx.x; i < 8192; i += 256) a += logf(rowse[i]);
    for (int i = threadIdx.x; i < 4096; i += 256) { b += bsum[i]; c += bdiag[i]; }
    #pragma unroll
    for (int off = 32; off; off >>= 1) {
        a += __shfl_xor(a, off, 64);
        b += __shfl_xor(b, off, 64);
        c += __shfl_xor(c, off, 64);
    }
    __shared__ float ra[4], rb[4], rc[4];
    const int wave = threadIdx.x >> 6, lane = threadIdx.x & 63;
    if (lane == 0) { ra[wave] = a; rb[wave] = b; rc[wave] = c; }
    __syncthreads();
    if (threadIdx.x == 0) {
        const float A = ra[0] + ra[1] + ra[2] + ra[3];
        const float B = rb[0] + rb[1] + rb[2] + rb[3];
        const float C = rc[0] + rc[1] + rc[2] + rc[3];
        const float diag_mean = C / 8192.f;
        out[0] = A / 8192.f - diag_mean;            // loss
        out[1] = diag_mean;                         // sim_pos
        out[2] = B / (8192.f * 8192.f);             // sim_mean
    }
}

// ---------------------------------------------------------------- launch
extern "C" void kernel_launch(void* const* d_in, const int* in_sizes, int n_in,
                              void* d_out, int out_size, void* d_ws, size_t ws_size,
                              hipStream_t stream) {
    const float* h = (const float*)d_in[0];   // [16384, 2048]
    const float* W = (const float*)d_in[1];   // [512, 2048]
    float* out = (float*)d_out;               // [3]

    char* ws = (char*)d_ws;
    float* norm2 = (float*)(ws);                            // 16384 f @ 0
    float* rowse = (float*)(ws + 65536);                    //  8192 f
    float* bsum  = (float*)(ws + 98304);                    //  4096 f used
    float* bdiag = (float*)(ws + 163840);                   //  4096 f used
    uchar* Z8    = (uchar*)(ws + 229376);                   // 16384x512 fp8 (8.39 MB)
    unsigned short* Wb = (unsigned short*)(ws + 8617984);   // 512x2048 bf16 (2 MB)
    unsigned short* hb = (unsigned short*)(ws + 10715136);  // 16384x2048 bf16 (67.1 MB)
    const size_t NEED_FAST = 10715136ull + 67108864ull;     // ~77.8 MB

    hipMemsetAsync(ws, 0, 229376, stream);    // zero atomic accumulators

    if (ws_size >= NEED_FAST) {
        const int nh = 16384 * 2048, nw = 512 * 2048;
        hipLaunchKernelGGL(cast_kernel, dim3(nh / 2048), dim3(256), 0, stream, h, hb, nh);
        hipLaunchKernelGGL(cast_kernel, dim3(nw / 2048), dim3(256), 0, stream, W, Wb, nw);
        hipLaunchKernelGGL(g1_main, dim3(4, 128), dim3(256), 0, stream, hb, Wb, Z8, norm2);
    } else {
        hipLaunchKernelGGL(g1_slow, dim3(4, 128), dim3(256), 0, stream, h, W, Z8, norm2);
    }
    hipLaunchKernelGGL(g2_main, dim3(64, 64), dim3(256), 0, stream, Z8, norm2, rowse, bsum, bdiag);
    hipLaunchKernelGGL(finalize_kernel, dim3(1), dim3(256), 0, stream, rowse, bsum, bdiag, out);
}

// Round 6
// 414.956 us; speedup vs baseline: 1.3550x; 1.3270x over previous
//
#include <hip/hip_runtime.h>

// InfoNCE fused pipeline (round 6):
//   cast   : h,W fp32 -> bf16
//   g1_main: Z = hb @ Wb^T (128x128, BK=32, m97 staging), epilogue quantizes
//            Z to fp8-e4m3 + norm^2 of the DEQUANTIZED values  [r4, proven]
//   g2_main: S = Z8[:8192] @ Z8[8192:]^T via MX fp8 MFMA 16x16x128 (scale=1.0),
//            128x128 tile, BK=128, 4 K-iters. ROUND-6 FIX: only bfr[4] frags
//            resident (r5 kept af[4]+bf[4] -> 512 B/thread scratch spill,
//            WRITE_SIZE 524 MB, kernel was HBM-bound on its own spill).
//   finalize: loss = mean(log(rowsumexp)) - mean(diag); sim_pos; sim_mean

typedef __attribute__((ext_vector_type(8))) short bf16x8;   // 8 bf16 = 4 VGPRs
typedef __attribute__((ext_vector_type(8))) short short8;
typedef __attribute__((ext_vector_type(4))) float floatx4;  // MFMA C/D frag
typedef __attribute__((ext_vector_type(8))) int   intx8;    // f8f6f4 A/B frag (32B)
typedef __attribute__((ext_vector_type(4))) int   intx4;
typedef unsigned char uchar;

__device__ __forceinline__ unsigned short f2bf(float f) {
    union { float f; unsigned u; } v; v.f = f;
    unsigned r = (v.u + 0x7FFFu + ((v.u >> 16) & 1u)) >> 16;   // RNE
    return (unsigned short)r;
}

// async global->LDS, 16B per lane. LDS dest = wave-uniform base + lane*16.
__device__ __forceinline__ void async_copy16(const void* g, void* l) {
    __builtin_amdgcn_global_load_lds(
        (const __attribute__((address_space(1))) void*)g,
        (__attribute__((address_space(3))) void*)l,
        16, 0, 0);
}

// ---------------------------------------------------------------- cast fp32->bf16
__global__ __launch_bounds__(256) void cast_kernel(
    const float* __restrict__ src, unsigned short* __restrict__ dst, int n)
{
    const int i = (blockIdx.x * 256 + threadIdx.x) * 8;
    if (i + 7 < n) {
        const float4 a = *reinterpret_cast<const float4*>(src + i);
        const float4 b = *reinterpret_cast<const float4*>(src + i + 4);
        short8 o;
        o[0] = (short)f2bf(a.x); o[1] = (short)f2bf(a.y);
        o[2] = (short)f2bf(a.z); o[3] = (short)f2bf(a.w);
        o[4] = (short)f2bf(b.x); o[5] = (short)f2bf(b.y);
        o[6] = (short)f2bf(b.z); o[7] = (short)f2bf(b.w);
        *reinterpret_cast<short8*>(dst + i) = o;
    }
}

// ---------------------------------------------------------------- g1_main (r4, proven)
__global__ __launch_bounds__(256) void g1_main(
    const unsigned short* __restrict__ hb, const unsigned short* __restrict__ Wb,
    uchar* __restrict__ Z8, float* __restrict__ norm2)
{
    __shared__ __align__(16) unsigned short As[128 * 32];
    __shared__ __align__(16) unsigned short Bs[128 * 32];

    const int bn = blockIdx.x;        // 0..3   (N=512)
    const int bm = blockIdx.y;        // 0..127 (M=16384)
    const int t = threadIdx.x;
    const int wave = t >> 6, lane = t & 63;
    const int wm = wave & 1, wn = wave >> 1;
    const int quad = lane >> 4, l15 = lane & 15;

    floatx4 acc[4][4];
    #pragma unroll
    for (int i = 0; i < 4; i++)
        #pragma unroll
        for (int j = 0; j < 4; j++) acc[i][j] = {0.f, 0.f, 0.f, 0.f};

    const int srow = lane >> 2, skcol = (lane & 3) * 8;
    unsigned short* lA0 = &As[(wave * 32 +  0) * 32];
    unsigned short* lA1 = &As[(wave * 32 + 16) * 32];
    unsigned short* lB0 = &Bs[(wave * 32 +  0) * 32];
    unsigned short* lB1 = &Bs[(wave * 32 + 16) * 32];
    const unsigned short* gA0 = hb + (size_t)(bm * 128 + wave * 32 + srow) * 2048 + skcol;
    const unsigned short* gA1 = gA0 + (size_t)16 * 2048;
    const unsigned short* gB0 = Wb + (size_t)(bn * 128 + wave * 32 + srow) * 2048 + skcol;
    const unsigned short* gB1 = gB0 + (size_t)16 * 2048;

    for (int k0 = 0; k0 < 2048; k0 += 32) {
        async_copy16(gA0 + k0, lA0);
        async_copy16(gA1 + k0, lA1);
        async_copy16(gB0 + k0, lB0);
        async_copy16(gB1 + k0, lB1);
        __syncthreads();
        bf16x8 af[4], bfr[4];
        #pragma unroll
        for (int i = 0; i < 4; i++)
            af[i] = *reinterpret_cast<const bf16x8*>(&As[(wm * 64 + i * 16 + l15) * 32 + quad * 8]);
        #pragma unroll
        for (int j = 0; j < 4; j++)
            bfr[j] = *reinterpret_cast<const bf16x8*>(&Bs[(wn * 64 + j * 16 + l15) * 32 + quad * 8]);
        #pragma unroll
        for (int i = 0; i < 4; i++)
            #pragma unroll
            for (int j = 0; j < 4; j++)
                acc[i][j] = __builtin_amdgcn_mfma_f32_16x16x32_bf16(af[i], bfr[j], acc[i][j], 0, 0, 0);
        __syncthreads();
    }

    #pragma unroll
    for (int i = 0; i < 4; i++) {
        #pragma unroll
        for (int r = 0; r < 4; r++) {
            const int row_g = bm * 128 + wm * 64 + i * 16 + quad * 4 + r;
            const int pk01 = __builtin_amdgcn_cvt_pk_fp8_f32(acc[i][0][r], acc[i][1][r], 0, 0);
            const int pk23 = __builtin_amdgcn_cvt_pk_fp8_f32(acc[i][2][r], acc[i][3][r], 0, 0);
            const size_t rbase = (size_t)row_g * 512 + bn * 128 + wn * 64 + l15;
            Z8[rbase +  0] = (uchar)(pk01 & 0xff);
            Z8[rbase + 16] = (uchar)((pk01 >> 8) & 0xff);
            Z8[rbase + 32] = (uchar)(pk23 & 0xff);
            Z8[rbase + 48] = (uchar)((pk23 >> 8) & 0xff);
            const float q0 = __builtin_amdgcn_cvt_f32_fp8(pk01, 0);
            const float q1 = __builtin_amdgcn_cvt_f32_fp8(pk01, 1);
            const float q2 = __builtin_amdgcn_cvt_f32_fp8(pk23, 0);
            const float q3 = __builtin_amdgcn_cvt_f32_fp8(pk23, 1);
            float p = q0 * q0 + q1 * q1 + q2 * q2 + q3 * q3;
            p += __shfl_xor(p, 1, 16);
            p += __shfl_xor(p, 2, 16);
            p += __shfl_xor(p, 4, 16);
            p += __shfl_xor(p, 8, 16);
            if (l15 == 0) atomicAdd(&norm2[row_g], p);
        }
    }
}

// ---------------------------------------------------------------- g1_slow (fallback, fp32 in)
__global__ __launch_bounds__(256) void g1_slow(
    const float* __restrict__ h, const float* __restrict__ W,
    uchar* __restrict__ Z8, float* __restrict__ norm2)
{
    __shared__ __align__(16) unsigned short As[128][40];
    __shared__ __align__(16) unsigned short Bs[128][40];

    const int bn = blockIdx.x, bm = blockIdx.y;
    const int t = threadIdx.x;
    const int wave = t >> 6, lane = t & 63;
    const int wm = wave & 1, wn = wave >> 1;
    const int quad = lane >> 4, l15 = lane & 15;

    floatx4 acc[4][4];
    #pragma unroll
    for (int i = 0; i < 4; i++)
        #pragma unroll
        for (int j = 0; j < 4; j++) acc[i][j] = {0.f, 0.f, 0.f, 0.f};

    const int lrow = t >> 1, lhalf = t & 1;
    const float* ga = h + (size_t)(bm * 128 + lrow) * 2048 + lhalf * 16;
    const float* gb = W + (size_t)(bn * 128 + lrow) * 2048 + lhalf * 16;

    for (int k0 = 0; k0 < 2048; k0 += 32) {
        #pragma unroll
        for (int c = 0; c < 4; c++) {
            const float4 va = *reinterpret_cast<const float4*>(ga + k0 + c * 4);
            const float4 vb = *reinterpret_cast<const float4*>(gb + k0 + c * 4);
            ushort4 ua = make_ushort4(f2bf(va.x), f2bf(va.y), f2bf(va.z), f2bf(va.w));
            ushort4 ub = make_ushort4(f2bf(vb.x), f2bf(vb.y), f2bf(vb.z), f2bf(vb.w));
            *reinterpret_cast<ushort4*>(&As[lrow][lhalf * 16 + c * 4]) = ua;
            *reinterpret_cast<ushort4*>(&Bs[lrow][lhalf * 16 + c * 4]) = ub;
        }
        __syncthreads();
        bf16x8 af[4], bfr[4];
        #pragma unroll
        for (int i = 0; i < 4; i++)
            af[i] = *reinterpret_cast<const bf16x8*>(&As[wm * 64 + i * 16 + l15][quad * 8]);
        #pragma unroll
        for (int j = 0; j < 4; j++)
            bfr[j] = *reinterpret_cast<const bf16x8*>(&Bs[wn * 64 + j * 16 + l15][quad * 8]);
        #pragma unroll
        for (int i = 0; i < 4; i++)
            #pragma unroll
            for (int j = 0; j < 4; j++)
                acc[i][j] = __builtin_amdgcn_mfma_f32_16x16x32_bf16(af[i], bfr[j], acc[i][j], 0, 0, 0);
        __syncthreads();
    }

    #pragma unroll
    for (int i = 0; i < 4; i++) {
        #pragma unroll
        for (int r = 0; r < 4; r++) {
            const int row_g = bm * 128 + wm * 64 + i * 16 + quad * 4 + r;
            const int pk01 = __builtin_amdgcn_cvt_pk_fp8_f32(acc[i][0][r], acc[i][1][r], 0, 0);
            const int pk23 = __builtin_amdgcn_cvt_pk_fp8_f32(acc[i][2][r], acc[i][3][r], 0, 0);
            const size_t rbase = (size_t)row_g * 512 + bn * 128 + wn * 64 + l15;
            Z8[rbase +  0] = (uchar)(pk01 & 0xff);
            Z8[rbase + 16] = (uchar)((pk01 >> 8) & 0xff);
            Z8[rbase + 32] = (uchar)(pk23 & 0xff);
            Z8[rbase + 48] = (uchar)((pk23 >> 8) & 0xff);
            const float q0 = __builtin_amdgcn_cvt_f32_fp8(pk01, 0);
            const float q1 = __builtin_amdgcn_cvt_f32_fp8(pk01, 1);
            const float q2 = __builtin_amdgcn_cvt_f32_fp8(pk23, 0);
            const float q3 = __builtin_amdgcn_cvt_f32_fp8(pk23, 1);
            float p = q0 * q0 + q1 * q1 + q2 * q2 + q3 * q3;
            p += __shfl_xor(p, 1, 16);
            p += __shfl_xor(p, 2, 16);
            p += __shfl_xor(p, 4, 16);
            p += __shfl_xor(p, 8, 16);
            if (l15 == 0) atomicAdd(&norm2[row_g], p);
        }
    }
}

// ---------------------------------------------------------------- g2_main
// S = Z8[:8192] @ Z8[8192:]^T via MX fp8 MFMA 16x16x128 (scale=1.0).
// 128x128 tile, BK=128 (32 KB LDS), 4 K-iters. XOR chunk swizzle as r4/r5.
// r6: only bfr[4] live (32 VGPRs) + one A-frag buffer -> no scratch spill.
__global__ __launch_bounds__(256, 2) void g2_main(
    const uchar* __restrict__ Z8, const float* __restrict__ norm2,
    float* __restrict__ rowse, float* __restrict__ bsum, float* __restrict__ bdiag)
{
    __shared__ __align__(16) uchar As[128 * 128];   // 16 KB
    __shared__ __align__(16) uchar Bs[128 * 128];   // 16 KB
    __shared__ float red[8];

    const int bn = blockIdx.x;        // 0..63
    const int bm = blockIdx.y;        // 0..63
    const int t = threadIdx.x;
    const int wave = t >> 6, lane = t & 63;
    const int wm = wave & 1, wn = wave >> 1;       // 64x64 quadrant per wave
    const int quad = lane >> 4, l15 = lane & 15;

    const uchar* gA = Z8 + (size_t)(bm * 128) * 512;
    const uchar* gB = Z8 + (size_t)(8192 + bn * 128) * 512;

    floatx4 acc[4][4];
    #pragma unroll
    for (int i = 0; i < 4; i++)
        #pragma unroll
        for (int j = 0; j < 4; j++) acc[i][j] = {0.f, 0.f, 0.f, 0.f};

    // fill map: one instr covers 8 rows x 128 B; lane l -> row l>>3, slot l&7
    const int frow = lane >> 3, fslot = lane & 7;

    // frag-read address components (lane's k-bytes = quad*32 .. +32)
    const int mA = wm * 64 + l15;                  // A row for i=0
    const int nB = wn * 64 + l15;                  // B row for j=0

    for (int ks = 0; ks < 4; ks++) {
        const int k0 = ks * 128;
        #pragma unroll
        for (int i = 0; i < 4; i++) {
            const int rT = wave * 32 + i * 8 + frow;                 // tile row
            const int src = rT * 512 + k0 + ((fslot ^ (rT & 7)) << 4);
            async_copy16(gA + src, &As[(wave * 32 + i * 8) * 128]);
            async_copy16(gB + src, &Bs[(wave * 32 + i * 8) * 128]);
        }
        __syncthreads();

        intx8 bfr[4];
        #pragma unroll
        for (int j = 0; j < 4; j++) {
            const int n = nB + j * 16;
            const int c0 = (2 * quad) ^ (n & 7);          // c1 = c0 ^ 1
            const intx4 lo = *reinterpret_cast<const intx4*>(&Bs[n * 128 + (c0 << 4)]);
            const intx4 hi = *reinterpret_cast<const intx4*>(&Bs[n * 128 + ((c0 ^ 1) << 4)]);
            bfr[j] = __builtin_shufflevector(lo, hi, 0, 1, 2, 3, 4, 5, 6, 7);
        }
        #pragma unroll
        for (int i = 0; i < 4; i++) {
            const int m = mA + i * 16;
            const int c0 = (2 * quad) ^ (m & 7);
            const intx4 lo = *reinterpret_cast<const intx4*>(&As[m * 128 + (c0 << 4)]);
            const intx4 hi = *reinterpret_cast<const intx4*>(&As[m * 128 + ((c0 ^ 1) << 4)]);
            const intx8 a = __builtin_shufflevector(lo, hi, 0, 1, 2, 3, 4, 5, 6, 7);
            #pragma unroll
            for (int j = 0; j < 4; j++)
                acc[i][j] = __builtin_amdgcn_mfma_scale_f32_16x16x128_f8f6f4(
                    a, bfr[j], acc[i][j], 0, 0, 0, 127, 0, 127);  // fp8/fp8, scale=1.0
        }
        __syncthreads();
    }

    // Fused epilogue: sim = dot * rsqrt(n2_i) * rsqrt(n2_j) / TEMP
    float rc4[4];
    #pragma unroll
    for (int j = 0; j < 4; j++)
        rc4[j] = rsqrtf(fmaxf(norm2[8192 + bn * 128 + wn * 64 + j * 16 + l15], 1e-30f));

    float s_total = 0.f, s_diag = 0.f;
    #pragma unroll
    for (int i = 0; i < 4; i++) {
        #pragma unroll
        for (int r = 0; r < 4; r++) {
            const int row_g = bm * 128 + wm * 64 + i * 16 + quad * 4 + r;
            const float rz = rsqrtf(fmaxf(norm2[row_g], 1e-30f));
            float rowexp = 0.f;
            #pragma unroll
            for (int j = 0; j < 4; j++) {
                const int col_g = bn * 128 + wn * 64 + j * 16 + l15;
                const float sim = acc[i][j][r] * rz * rc4[j] * 10.0f;  // 1/TEMP
                s_total += sim;
                rowexp += __expf(sim);
                if (col_g == row_g) s_diag += sim;
            }
            rowexp += __shfl_xor(rowexp, 1, 16);
            rowexp += __shfl_xor(rowexp, 2, 16);
            rowexp += __shfl_xor(rowexp, 4, 16);
            rowexp += __shfl_xor(rowexp, 8, 16);
            if (l15 == 0) atomicAdd(&rowse[row_g], rowexp);
        }
    }
    #pragma unroll
    for (int off = 32; off; off >>= 1) {
        s_total += __shfl_xor(s_total, off, 64);
        s_diag  += __shfl_xor(s_diag, off, 64);
    }
    if (lane == 0) { red[wave] = s_total; red[4 + wave] = s_diag; }
    __syncthreads();
    if (t == 0) {
        bsum[bm * 64 + bn]  = red[0] + red[1] + red[2] + red[3];
        bdiag[bm * 64 + bn] = red[4] + red[5] + red[6] + red[7];
    }
}

// ---------------------------------------------------------------- finalize
__global__ __launch_bounds__(256) void finalize_kernel(
    const float* __restrict__ rowse, const float* __restrict__ bsum,
    const float* __restrict__ bdiag, float* __restrict__ out)
{
    float a = 0.f, b = 0.f, c = 0.f;
    for (int i = threadIdx.x; i < 8192; i += 256) a += logf(rowse[i]);
    for (int i = threadIdx.x; i < 4096; i += 256) { b += bsum[i]; c += bdiag[i]; }
    #pragma unroll
    for (int off = 32; off; off >>= 1) {
        a += __shfl_xor(a, off, 64);
        b += __shfl_xor(b, off, 64);
        c += __shfl_xor(c, off, 64);
    }
    __shared__ float ra[4], rb[4], rc[4];
    const int wave = threadIdx.x >> 6, lane = threadIdx.x & 63;
    if (lane == 0) { ra[wave] = a; rb[wave] = b; rc[wave] = c; }
    __syncthreads();
    if (threadIdx.x == 0) {
        const float A = ra[0] + ra[1] + ra[2] + ra[3];
        const float B = rb[0] + rb[1] + rb[2] + rb[3];
        const float C = rc[0] + rc[1] + rc[2] + rc[3];
        const float diag_mean = C / 8192.f;
        out[0] = A / 8192.f - diag_mean;            // loss
        out[1] = diag_mean;                         // sim_pos
        out[2] = B / (8192.f * 8192.f);             // sim_mean
    }
}

// ---------------------------------------------------------------- launch
extern "C" void kernel_launch(void* const* d_in, const int* in_sizes, int n_in,
                              void* d_out, int out_size, void* d_ws, size_t ws_size,
                              hipStream_t stream) {
    const float* h = (const float*)d_in[0];   // [16384, 2048]
    const float* W = (const float*)d_in[1];   // [512, 2048]
    float* out = (float*)d_out;               // [3]

    char* ws = (char*)d_ws;
    float* norm2 = (float*)(ws);                            // 16384 f @ 0
    float* rowse = (float*)(ws + 65536);                    //  8192 f
    float* bsum  = (float*)(ws + 98304);                    //  4096 f used
    float* bdiag = (float*)(ws + 163840);                   //  4096 f used
    uchar* Z8    = (uchar*)(ws + 229376);                   // 16384x512 fp8 (8.39 MB)
    unsigned short* Wb = (unsigned short*)(ws + 8617984);   // 512x2048 bf16 (2 MB)
    unsigned short* hb = (unsigned short*)(ws + 10715136);  // 16384x2048 bf16 (67.1 MB)
    const size_t NEED_FAST = 10715136ull + 67108864ull;     // ~77.8 MB

    hipMemsetAsync(ws, 0, 229376, stream);    // zero atomic accumulators

    if (ws_size >= NEED_FAST) {
        const int nh = 16384 * 2048, nw = 512 * 2048;
        hipLaunchKernelGGL(cast_kernel, dim3(nh / 2048), dim3(256), 0, stream, h, hb, nh);
        hipLaunchKernelGGL(cast_kernel, dim3(nw / 2048), dim3(256), 0, stream, W, Wb, nw);
        hipLaunchKernelGGL(g1_main, dim3(4, 128), dim3(256), 0, stream, hb, Wb, Z8, norm2);
    } else {
        hipLaunchKernelGGL(g1_slow, dim3(4, 128), dim3(256), 0, stream, h, W, Z8, norm2);
    }
    hipLaunchKernelGGL(g2_main, dim3(64, 64), dim3(256), 0, stream, Z8, norm2, rowse, bsum, bdiag);
    hipLaunchKernelGGL(finalize_kernel, dim3(1), dim3(256), 0, stream, rowse, bsum, bdiag, out);
}

// Round 7
// 392.695 us; speedup vs baseline: 1.4318x; 1.0567x over previous
//
#include <hip/hip_runtime.h>

// InfoNCE fused pipeline (round 7):
//   cast   : h,W fp32 -> bf16
//   g1_main: Z = hb @ Wb^T (128x128, BK=32, m97 staging) [core unchanged since r2];
//            epilogue quantizes to fp8-e4m3 and stores Z8F in FRAG LAYOUT:
//            block of 512 B per (row-group g=row>>4, k-chunk c=k>>5), byte
//            addr = (g*16+c)*512 + lane*8 where lane = quad*16 + (row&15)
//            [fp8 16x16x32 A/B mapping, r4-verified]. norm^2 of dequantized.
//   g2_main: S = Z8F[:8192] @ Z8F[8192:]^T -- NO LDS, NO BARRIERS: lanes load
//            frags straight from global (wave-coalesced b64, L2/L3-served),
//            fp8 16x16x32 MFMA, 128x128 tile, fused InfoNCE epilogue.
//   finalize: loss = mean(log(rowsumexp)) - mean(diag); sim_pos; sim_mean

typedef __attribute__((ext_vector_type(8))) short bf16x8;   // 8 bf16 = 4 VGPRs
typedef __attribute__((ext_vector_type(8))) short short8;
typedef __attribute__((ext_vector_type(4))) float floatx4;  // MFMA C/D frag
typedef unsigned char uchar;

__device__ __forceinline__ unsigned short f2bf(float f) {
    union { float f; unsigned u; } v; v.f = f;
    unsigned r = (v.u + 0x7FFFu + ((v.u >> 16) & 1u)) >> 16;   // RNE
    return (unsigned short)r;
}

// async global->LDS, 16B per lane. LDS dest = wave-uniform base + lane*16.
__device__ __forceinline__ void async_copy16(const void* g, void* l) {
    __builtin_amdgcn_global_load_lds(
        (const __attribute__((address_space(1))) void*)g,
        (__attribute__((address_space(3))) void*)l,
        16, 0, 0);
}

// ---------------------------------------------------------------- cast fp32->bf16
__global__ __launch_bounds__(256) void cast_kernel(
    const float* __restrict__ src, unsigned short* __restrict__ dst, int n)
{
    const int i = (blockIdx.x * 256 + threadIdx.x) * 8;
    if (i + 7 < n) {
        const float4 a = *reinterpret_cast<const float4*>(src + i);
        const float4 b = *reinterpret_cast<const float4*>(src + i + 4);
        short8 o;
        o[0] = (short)f2bf(a.x); o[1] = (short)f2bf(a.y);
        o[2] = (short)f2bf(a.z); o[3] = (short)f2bf(a.w);
        o[4] = (short)f2bf(b.x); o[5] = (short)f2bf(b.y);
        o[6] = (short)f2bf(b.z); o[7] = (short)f2bf(b.w);
        *reinterpret_cast<short8*>(dst + i) = o;
    }
}

// store helper: fp8 byte for (row_g, col_g) into frag-layout Z8F
__device__ __forceinline__ size_t fl_off(int row_g, int col_g) {
    const int g = row_g >> 4, r15 = row_g & 15;
    const int c = col_g >> 5, q = (col_g >> 3) & 3, b = col_g & 7;
    return ((size_t)g * 16 + c) * 512 + (size_t)(q * 16 + r15) * 8 + b;
}

// ---------------------------------------------------------------- g1_main
__global__ __launch_bounds__(256) void g1_main(
    const unsigned short* __restrict__ hb, const unsigned short* __restrict__ Wb,
    uchar* __restrict__ Z8F, float* __restrict__ norm2)
{
    __shared__ __align__(16) unsigned short As[128 * 32];
    __shared__ __align__(16) unsigned short Bs[128 * 32];

    const int bn = blockIdx.x;        // 0..3   (N=512)
    const int bm = blockIdx.y;        // 0..127 (M=16384)
    const int t = threadIdx.x;
    const int wave = t >> 6, lane = t & 63;
    const int wm = wave & 1, wn = wave >> 1;
    const int quad = lane >> 4, l15 = lane & 15;

    floatx4 acc[4][4];
    #pragma unroll
    for (int i = 0; i < 4; i++)
        #pragma unroll
        for (int j = 0; j < 4; j++) acc[i][j] = {0.f, 0.f, 0.f, 0.f};

    const int srow = lane >> 2, skcol = (lane & 3) * 8;
    unsigned short* lA0 = &As[(wave * 32 +  0) * 32];
    unsigned short* lA1 = &As[(wave * 32 + 16) * 32];
    unsigned short* lB0 = &Bs[(wave * 32 +  0) * 32];
    unsigned short* lB1 = &Bs[(wave * 32 + 16) * 32];
    const unsigned short* gA0 = hb + (size_t)(bm * 128 + wave * 32 + srow) * 2048 + skcol;
    const unsigned short* gA1 = gA0 + (size_t)16 * 2048;
    const unsigned short* gB0 = Wb + (size_t)(bn * 128 + wave * 32 + srow) * 2048 + skcol;
    const unsigned short* gB1 = gB0 + (size_t)16 * 2048;

    for (int k0 = 0; k0 < 2048; k0 += 32) {
        async_copy16(gA0 + k0, lA0);
        async_copy16(gA1 + k0, lA1);
        async_copy16(gB0 + k0, lB0);
        async_copy16(gB1 + k0, lB1);
        __syncthreads();
        bf16x8 af[4], bfr[4];
        #pragma unroll
        for (int i = 0; i < 4; i++)
            af[i] = *reinterpret_cast<const bf16x8*>(&As[(wm * 64 + i * 16 + l15) * 32 + quad * 8]);
        #pragma unroll
        for (int j = 0; j < 4; j++)
            bfr[j] = *reinterpret_cast<const bf16x8*>(&Bs[(wn * 64 + j * 16 + l15) * 32 + quad * 8]);
        #pragma unroll
        for (int i = 0; i < 4; i++)
            #pragma unroll
            for (int j = 0; j < 4; j++)
                acc[i][j] = __builtin_amdgcn_mfma_f32_16x16x32_bf16(af[i], bfr[j], acc[i][j], 0, 0, 0);
        __syncthreads();
    }

    // Epilogue: quantize, store in frag layout, norm^2 of dequantized values.
    #pragma unroll
    for (int i = 0; i < 4; i++) {
        #pragma unroll
        for (int r = 0; r < 4; r++) {
            const int row_g = bm * 128 + wm * 64 + i * 16 + quad * 4 + r;
            const int pk01 = __builtin_amdgcn_cvt_pk_fp8_f32(acc[i][0][r], acc[i][1][r], 0, 0);
            const int pk23 = __builtin_amdgcn_cvt_pk_fp8_f32(acc[i][2][r], acc[i][3][r], 0, 0);
            const uchar q8[4] = { (uchar)(pk01 & 0xff), (uchar)((pk01 >> 8) & 0xff),
                                  (uchar)(pk23 & 0xff), (uchar)((pk23 >> 8) & 0xff) };
            #pragma unroll
            for (int j = 0; j < 4; j++) {
                const int col_g = bn * 128 + wn * 64 + j * 16 + l15;
                Z8F[fl_off(row_g, col_g)] = q8[j];
            }
            const float q0 = __builtin_amdgcn_cvt_f32_fp8(pk01, 0);
            const float q1 = __builtin_amdgcn_cvt_f32_fp8(pk01, 1);
            const float q2 = __builtin_amdgcn_cvt_f32_fp8(pk23, 0);
            const float q3 = __builtin_amdgcn_cvt_f32_fp8(pk23, 1);
            float p = q0 * q0 + q1 * q1 + q2 * q2 + q3 * q3;
            p += __shfl_xor(p, 1, 16);
            p += __shfl_xor(p, 2, 16);
            p += __shfl_xor(p, 4, 16);
            p += __shfl_xor(p, 8, 16);
            if (l15 == 0) atomicAdd(&norm2[row_g], p);
        }
    }
}

// ---------------------------------------------------------------- g1_slow (fallback, fp32 in)
__global__ __launch_bounds__(256) void g1_slow(
    const float* __restrict__ h, const float* __restrict__ W,
    uchar* __restrict__ Z8F, float* __restrict__ norm2)
{
    __shared__ __align__(16) unsigned short As[128][40];
    __shared__ __align__(16) unsigned short Bs[128][40];

    const int bn = blockIdx.x, bm = blockIdx.y;
    const int t = threadIdx.x;
    const int wave = t >> 6, lane = t & 63;
    const int wm = wave & 1, wn = wave >> 1;
    const int quad = lane >> 4, l15 = lane & 15;

    floatx4 acc[4][4];
    #pragma unroll
    for (int i = 0; i < 4; i++)
        #pragma unroll
        for (int j = 0; j < 4; j++) acc[i][j] = {0.f, 0.f, 0.f, 0.f};

    const int lrow = t >> 1, lhalf = t & 1;
    const float* ga = h + (size_t)(bm * 128 + lrow) * 2048 + lhalf * 16;
    const float* gb = W + (size_t)(bn * 128 + lrow) * 2048 + lhalf * 16;

    for (int k0 = 0; k0 < 2048; k0 += 32) {
        #pragma unroll
        for (int c = 0; c < 4; c++) {
            const float4 va = *reinterpret_cast<const float4*>(ga + k0 + c * 4);
            const float4 vb = *reinterpret_cast<const float4*>(gb + k0 + c * 4);
            ushort4 ua = make_ushort4(f2bf(va.x), f2bf(va.y), f2bf(va.z), f2bf(va.w));
            ushort4 ub = make_ushort4(f2bf(vb.x), f2bf(vb.y), f2bf(vb.z), f2bf(vb.w));
            *reinterpret_cast<ushort4*>(&As[lrow][lhalf * 16 + c * 4]) = ua;
            *reinterpret_cast<ushort4*>(&Bs[lrow][lhalf * 16 + c * 4]) = ub;
        }
        __syncthreads();
        bf16x8 af[4], bfr[4];
        #pragma unroll
        for (int i = 0; i < 4; i++)
            af[i] = *reinterpret_cast<const bf16x8*>(&As[wm * 64 + i * 16 + l15][quad * 8]);
        #pragma unroll
        for (int j = 0; j < 4; j++)
            bfr[j] = *reinterpret_cast<const bf16x8*>(&Bs[wn * 64 + j * 16 + l15][quad * 8]);
        #pragma unroll
        for (int i = 0; i < 4; i++)
            #pragma unroll
            for (int j = 0; j < 4; j++)
                acc[i][j] = __builtin_amdgcn_mfma_f32_16x16x32_bf16(af[i], bfr[j], acc[i][j], 0, 0, 0);
        __syncthreads();
    }

    #pragma unroll
    for (int i = 0; i < 4; i++) {
        #pragma unroll
        for (int r = 0; r < 4; r++) {
            const int row_g = bm * 128 + wm * 64 + i * 16 + quad * 4 + r;
            const int pk01 = __builtin_amdgcn_cvt_pk_fp8_f32(acc[i][0][r], acc[i][1][r], 0, 0);
            const int pk23 = __builtin_amdgcn_cvt_pk_fp8_f32(acc[i][2][r], acc[i][3][r], 0, 0);
            const uchar q8[4] = { (uchar)(pk01 & 0xff), (uchar)((pk01 >> 8) & 0xff),
                                  (uchar)(pk23 & 0xff), (uchar)((pk23 >> 8) & 0xff) };
            #pragma unroll
            for (int j = 0; j < 4; j++) {
                const int col_g = bn * 128 + wn * 64 + j * 16 + l15;
                Z8F[fl_off(row_g, col_g)] = q8[j];
            }
            const float q0 = __builtin_amdgcn_cvt_f32_fp8(pk01, 0);
            const float q1 = __builtin_amdgcn_cvt_f32_fp8(pk01, 1);
            const float q2 = __builtin_amdgcn_cvt_f32_fp8(pk23, 0);
            const float q3 = __builtin_amdgcn_cvt_f32_fp8(pk23, 1);
            float p = q0 * q0 + q1 * q1 + q2 * q2 + q3 * q3;
            p += __shfl_xor(p, 1, 16);
            p += __shfl_xor(p, 2, 16);
            p += __shfl_xor(p, 4, 16);
            p += __shfl_xor(p, 8, 16);
            if (l15 == 0) atomicAdd(&norm2[row_g], p);
        }
    }
}

// ---------------------------------------------------------------- g2_main
// S = Z8F[:8192g] @ Z8F[8192g:]^T, fp8 16x16x32 MFMA, 128x128 tile.
// NO LDS / NO BARRIERS: frags loaded directly from global in frag layout
// (wave-coalesced dwordx2), reuse served by L2/L3 (Z8F = 8.4 MB).
__global__ __launch_bounds__(256, 2) void g2_main(
    const uchar* __restrict__ Z8F, const float* __restrict__ norm2,
    float* __restrict__ rowse, float* __restrict__ bsum, float* __restrict__ bdiag)
{
    __shared__ float red[8];

    const int bn = blockIdx.x;        // 0..63
    const int bm = blockIdx.y;        // 0..63
    const int t = threadIdx.x;
    const int wave = t >> 6, lane = t & 63;
    const int wm = wave & 1, wn = wave >> 1;       // 64x64 quadrant per wave
    const int quad = lane >> 4, l15 = lane & 15;

    floatx4 acc[4][4];
    #pragma unroll
    for (int i = 0; i < 4; i++)
        #pragma unroll
        for (int j = 0; j < 4; j++) acc[i][j] = {0.f, 0.f, 0.f, 0.f};

    // frag-layout bases: group stride = 16 chunks * 512 B = 8192 B
    const uchar* baseA = Z8F + ((size_t)(bm * 8 + wm * 4) * 16) * 512 + lane * 8;
    const uchar* baseB = Z8F + ((size_t)(512 + bn * 8 + wn * 4) * 16) * 512 + lane * 8;

    #pragma unroll 4
    for (int c = 0; c < 16; c++) {
        long a[4], b[4];
        #pragma unroll
        for (int i = 0; i < 4; i++) {
            a[i] = *reinterpret_cast<const long*>(baseA + i * 8192 + c * 512);
            b[i] = *reinterpret_cast<const long*>(baseB + i * 8192 + c * 512);
        }
        #pragma unroll
        for (int i = 0; i < 4; i++)
            #pragma unroll
            for (int j = 0; j < 4; j++)
                acc[i][j] = __builtin_amdgcn_mfma_f32_16x16x32_fp8_fp8(a[i], b[j], acc[i][j], 0, 0, 0);
    }

    // Fused epilogue: sim = dot * rsqrt(n2_i) * rsqrt(n2_j) / TEMP
    float rc4[4];
    #pragma unroll
    for (int j = 0; j < 4; j++)
        rc4[j] = rsqrtf(fmaxf(norm2[8192 + bn * 128 + wn * 64 + j * 16 + l15], 1e-30f));

    float s_total = 0.f, s_diag = 0.f;
    #pragma unroll
    for (int i = 0; i < 4; i++) {
        #pragma unroll
        for (int r = 0; r < 4; r++) {
            const int row_g = bm * 128 + wm * 64 + i * 16 + quad * 4 + r;
            const float rz = rsqrtf(fmaxf(norm2[row_g], 1e-30f));
            float rowexp = 0.f;
            #pragma unroll
            for (int j = 0; j < 4; j++) {
                const int col_g = bn * 128 + wn * 64 + j * 16 + l15;
                const float sim = acc[i][j][r] * rz * rc4[j] * 10.0f;  // 1/TEMP
                s_total += sim;
                rowexp += __expf(sim);
                if (col_g == row_g) s_diag += sim;
            }
            rowexp += __shfl_xor(rowexp, 1, 16);
            rowexp += __shfl_xor(rowexp, 2, 16);
            rowexp += __shfl_xor(rowexp, 4, 16);
            rowexp += __shfl_xor(rowexp, 8, 16);
            if (l15 == 0) atomicAdd(&rowse[row_g], rowexp);
        }
    }
    #pragma unroll
    for (int off = 32; off; off >>= 1) {
        s_total += __shfl_xor(s_total, off, 64);
        s_diag  += __shfl_xor(s_diag, off, 64);
    }
    if (lane == 0) { red[wave] = s_total; red[4 + wave] = s_diag; }
    __syncthreads();
    if (t == 0) {
        bsum[bm * 64 + bn]  = red[0] + red[1] + red[2] + red[3];
        bdiag[bm * 64 + bn] = red[4] + red[5] + red[6] + red[7];
    }
}

// ---------------------------------------------------------------- finalize
__global__ __launch_bounds__(256) void finalize_kernel(
    const float* __restrict__ rowse, const float* __restrict__ bsum,
    const float* __restrict__ bdiag, float* __restrict__ out)
{
    float a = 0.f, b = 0.f, c = 0.f;
    for (int i = threadIdx.x; i < 8192; i += 256) a += logf(rowse[i]);
    for (int i = threadIdx.x; i < 4096; i += 256) { b += bsum[i]; c += bdiag[i]; }
    #pragma unroll
    for (int off = 32; off; off >>= 1) {
        a += __shfl_xor(a, off, 64);
        b += __shfl_xor(b, off, 64);
        c += __shfl_xor(c, off, 64);
    }
    __shared__ float ra[4], rb[4], rc[4];
    const int wave = threadIdx.x >> 6, lane = threadIdx.x & 63;
    if (lane == 0) { ra[wave] = a; rb[wave] = b; rc[wave] = c; }
    __syncthreads();
    if (threadIdx.x == 0) {
        const float A = ra[0] + ra[1] + ra[2] + ra[3];
        const float B = rb[0] + rb[1] + rb[2] + rb[3];
        const float C = rc[0] + rc[1] + rc[2] + rc[3];
        const float diag_mean = C / 8192.f;
        out[0] = A / 8192.f - diag_mean;            // loss
        out[1] = diag_mean;                         // sim_pos
        out[2] = B / (8192.f * 8192.f);             // sim_mean
    }
}

// ---------------------------------------------------------------- launch
extern "C" void kernel_launch(void* const* d_in, const int* in_sizes, int n_in,
                              void* d_out, int out_size, void* d_ws, size_t ws_size,
                              hipStream_t stream) {
    const float* h = (const float*)d_in[0];   // [16384, 2048]
    const float* W = (const float*)d_in[1];   // [512, 2048]
    float* out = (float*)d_out;               // [3]

    char* ws = (char*)d_ws;
    float* norm2 = (float*)(ws);                            // 16384 f @ 0
    float* rowse = (float*)(ws + 65536);                    //  8192 f
    float* bsum  = (float*)(ws + 98304);                    //  4096 f used
    float* bdiag = (float*)(ws + 163840);                   //  4096 f used
    uchar* Z8F   = (uchar*)(ws + 229376);                   // frag-layout fp8 (8.39 MB)
    unsigned short* Wb = (unsigned short*)(ws + 8617984);   // 512x2048 bf16 (2 MB)
    unsigned short* hb = (unsigned short*)(ws + 10715136);  // 16384x2048 bf16 (67.1 MB)
    const size_t NEED_FAST = 10715136ull + 67108864ull;     // ~77.8 MB

    hipMemsetAsync(ws, 0, 229376, stream);    // zero atomic accumulators

    if (ws_size >= NEED_FAST) {
        const int nh = 16384 * 2048, nw = 512 * 2048;
        hipLaunchKernelGGL(cast_kernel, dim3(nh / 2048), dim3(256), 0, stream, h, hb, nh);
        hipLaunchKernelGGL(cast_kernel, dim3(nw / 2048), dim3(256), 0, stream, W, Wb, nw);
        hipLaunchKernelGGL(g1_main, dim3(4, 128), dim3(256), 0, stream, hb, Wb, Z8F, norm2);
    } else {
        hipLaunchKernelGGL(g1_slow, dim3(4, 128), dim3(256), 0, stream, h, W, Z8F, norm2);
    }
    hipLaunchKernelGGL(g2_main, dim3(64, 64), dim3(256), 0, stream, Z8F, norm2, rowse, bsum, bdiag);
    hipLaunchKernelGGL(finalize_kernel, dim3(1), dim3(256), 0, stream, rowse, bsum, bdiag, out);
}

// Round 8
// 329.451 us; speedup vs baseline: 1.7066x; 1.1920x over previous
//
#include <hip/hip_runtime.h>

// InfoNCE fused pipeline (round 8):
//   cast   : h -> fp8 e4m3 (scale 1), W -> fp8 (scale 32: lifts W~N(0,1/2048)
//            out of e4m3 denormal range; cosine is scale-invariant)
//   g1_main: Z' = h8 @ W8^T, fp8 16x16x32 MFMA, 128x128 tile, BK=64 bytes,
//            m97 global_load_lds staging + (row>>1)&3 slot swizzle (2-way=free);
//            epilogue stores Z8F in g2's frag layout + norm^2 of dequantized.
//   g2_main: S = Z8F[:8192g] @ Z8F[8192g:]^T -- r7 streaming K-loop (no LDS in
//            loop, no barriers, no spill) + SLIMMED epilogue: exp2-fold,
//            uniform diag branch, LDS-batched row reduction (no shuffles,
//            half the atomics).
//   finalize: loss = mean(log(rowsumexp)) - mean(diag); sim_pos; sim_mean

typedef __attribute__((ext_vector_type(8))) short bf16x8;
typedef __attribute__((ext_vector_type(4))) float floatx4;  // MFMA C/D frag
typedef unsigned char uchar;

__device__ __forceinline__ unsigned short f2bf(float f) {
    union { float f; unsigned u; } v; v.f = f;
    unsigned r = (v.u + 0x7FFFu + ((v.u >> 16) & 1u)) >> 16;   // RNE
    return (unsigned short)r;
}

// async global->LDS, 16B per lane. LDS dest = wave-uniform base + lane*16.
__device__ __forceinline__ void async_copy16(const void* g, void* l) {
    __builtin_amdgcn_global_load_lds(
        (const __attribute__((address_space(1))) void*)g,
        (__attribute__((address_space(3))) void*)l,
        16, 0, 0);
}

// ---------------------------------------------------------------- cast fp32->fp8
__global__ __launch_bounds__(256) void cast_fp8_kernel(
    const float* __restrict__ src, uchar* __restrict__ dst, int n, float scale)
{
    const int i = (blockIdx.x * 256 + threadIdx.x) * 8;
    if (i + 7 < n) {
        float4 a = *reinterpret_cast<const float4*>(src + i);
        float4 b = *reinterpret_cast<const float4*>(src + i + 4);
        const int p01 = __builtin_amdgcn_cvt_pk_fp8_f32(a.x * scale, a.y * scale, 0, 0);
        const int p23 = __builtin_amdgcn_cvt_pk_fp8_f32(a.z * scale, a.w * scale, 0, 0);
        const int p45 = __builtin_amdgcn_cvt_pk_fp8_f32(b.x * scale, b.y * scale, 0, 0);
        const int p67 = __builtin_amdgcn_cvt_pk_fp8_f32(b.z * scale, b.w * scale, 0, 0);
        int2 w;
        w.x = (p01 & 0xffff) | (p23 << 16);
        w.y = (p45 & 0xffff) | (p67 << 16);
        *reinterpret_cast<int2*>(dst + i) = w;
    }
}

// store helper: fp8 byte for (row_g, col_g) into frag-layout Z8F
__device__ __forceinline__ size_t fl_off(int row_g, int col_g) {
    const int g = row_g >> 4, r15 = row_g & 15;
    const int c = col_g >> 5, q = (col_g >> 3) & 3, b = col_g & 7;
    return ((size_t)g * 16 + c) * 512 + (size_t)(q * 16 + r15) * 8 + b;
}

// ---------------------------------------------------------------- g1_main (fp8 in)
// Z' = h8[16384,2048] @ W8[512,2048]^T, 128x128 tile, BK=64 B, 32 K-iters.
__global__ __launch_bounds__(256) void g1_main(
    const uchar* __restrict__ h8, const uchar* __restrict__ W8,
    uchar* __restrict__ Z8F, float* __restrict__ norm2)
{
    __shared__ __align__(16) uchar As[128 * 64];   // 8 KB
    __shared__ __align__(16) uchar Bs[128 * 64];   // 8 KB

    const int bn = blockIdx.x;        // 0..3   (N=512)
    const int bm = blockIdx.y;        // 0..127 (M=16384)
    const int t = threadIdx.x;
    const int wave = t >> 6, lane = t & 63;
    const int wm = wave & 1, wn = wave >> 1;
    const int quad = lane >> 4, l15 = lane & 15;

    floatx4 acc[4][4];
    #pragma unroll
    for (int i = 0; i < 4; i++)
        #pragma unroll
        for (int j = 0; j < 4; j++) acc[i][j] = {0.f, 0.f, 0.f, 0.f};

    // staging: wave w covers tile rows [w*32, w*32+32), two 1KB instrs of 16 rows.
    // physical slot p = lane&3; LDS is row-major; global source slot = p ^ ((row>>1)&3)
    const int srow0 = wave * 32 + (lane >> 2);
    const int srow1 = srow0 + 16;
    const int p = lane & 3;
    const int sw0 = (p ^ ((srow0 >> 1) & 3)) << 4;
    const int sw1 = (p ^ ((srow1 >> 1) & 3)) << 4;
    const uchar* gA0 = h8 + (size_t)(bm * 128 + srow0) * 2048 + sw0;
    const uchar* gA1 = h8 + (size_t)(bm * 128 + srow1) * 2048 + sw1;
    const uchar* gB0 = W8 + (size_t)(bn * 128 + srow0) * 2048 + sw0;
    const uchar* gB1 = W8 + (size_t)(bn * 128 + srow1) * 2048 + sw1;
    uchar* lA0 = &As[(wave * 32 +  0) * 64];
    uchar* lA1 = &As[(wave * 32 + 16) * 64];
    uchar* lB0 = &Bs[(wave * 32 +  0) * 64];
    uchar* lB1 = &Bs[(wave * 32 + 16) * 64];

    for (int k0 = 0; k0 < 2048; k0 += 64) {
        async_copy16(gA0 + k0, lA0);
        async_copy16(gA1 + k0, lA1);
        async_copy16(gB0 + k0, lB0);
        async_copy16(gB1 + k0, lB1);
        __syncthreads();
        #pragma unroll
        for (int ch = 0; ch < 2; ch++) {
            const int s = ch * 2 + (quad >> 1);
            const int sub = (quad & 1) * 8;
            long a[4], b[4];
            #pragma unroll
            for (int i = 0; i < 4; i++) {
                const int row = wm * 64 + i * 16 + l15;
                a[i] = *reinterpret_cast<const long*>(
                    &As[row * 64 + ((s ^ ((row >> 1) & 3)) << 4) + sub]);
            }
            #pragma unroll
            for (int j = 0; j < 4; j++) {
                const int row = wn * 64 + j * 16 + l15;
                b[j] = *reinterpret_cast<const long*>(
                    &Bs[row * 64 + ((s ^ ((row >> 1) & 3)) << 4) + sub]);
            }
            #pragma unroll
            for (int i = 0; i < 4; i++)
                #pragma unroll
                for (int j = 0; j < 4; j++)
                    acc[i][j] = __builtin_amdgcn_mfma_f32_16x16x32_fp8_fp8(
                        a[i], b[j], acc[i][j], 0, 0, 0);
        }
        __syncthreads();
    }

    // Epilogue: quantize, store frag layout, norm^2 of dequantized [r7, proven]
    #pragma unroll
    for (int i = 0; i < 4; i++) {
        #pragma unroll
        for (int r = 0; r < 4; r++) {
            const int row_g = bm * 128 + wm * 64 + i * 16 + quad * 4 + r;
            const int pk01 = __builtin_amdgcn_cvt_pk_fp8_f32(acc[i][0][r], acc[i][1][r], 0, 0);
            const int pk23 = __builtin_amdgcn_cvt_pk_fp8_f32(acc[i][2][r], acc[i][3][r], 0, 0);
            const uchar q8[4] = { (uchar)(pk01 & 0xff), (uchar)((pk01 >> 8) & 0xff),
                                  (uchar)(pk23 & 0xff), (uchar)((pk23 >> 8) & 0xff) };
            #pragma unroll
            for (int j = 0; j < 4; j++) {
                const int col_g = bn * 128 + wn * 64 + j * 16 + l15;
                Z8F[fl_off(row_g, col_g)] = q8[j];
            }
            const float q0 = __builtin_amdgcn_cvt_f32_fp8(pk01, 0);
            const float q1 = __builtin_amdgcn_cvt_f32_fp8(pk01, 1);
            const float q2 = __builtin_amdgcn_cvt_f32_fp8(pk23, 0);
            const float q3 = __builtin_amdgcn_cvt_f32_fp8(pk23, 1);
            float pw = q0 * q0 + q1 * q1 + q2 * q2 + q3 * q3;
            pw += __shfl_xor(pw, 1, 16);
            pw += __shfl_xor(pw, 2, 16);
            pw += __shfl_xor(pw, 4, 16);
            pw += __shfl_xor(pw, 8, 16);
            if (l15 == 0) atomicAdd(&norm2[row_g], pw);
        }
    }
}

// ---------------------------------------------------------------- g1_slow (fallback, fp32 in)
__global__ __launch_bounds__(256) void g1_slow(
    const float* __restrict__ h, const float* __restrict__ W,
    uchar* __restrict__ Z8F, float* __restrict__ norm2)
{
    __shared__ __align__(16) unsigned short As[128][40];
    __shared__ __align__(16) unsigned short Bs[128][40];

    const int bn = blockIdx.x, bm = blockIdx.y;
    const int t = threadIdx.x;
    const int wave = t >> 6, lane = t & 63;
    const int wm = wave & 1, wn = wave >> 1;
    const int quad = lane >> 4, l15 = lane & 15;

    floatx4 acc[4][4];
    #pragma unroll
    for (int i = 0; i < 4; i++)
        #pragma unroll
        for (int j = 0; j < 4; j++) acc[i][j] = {0.f, 0.f, 0.f, 0.f};

    const int lrow = t >> 1, lhalf = t & 1;
    const float* ga = h + (size_t)(bm * 128 + lrow) * 2048 + lhalf * 16;
    const float* gb = W + (size_t)(bn * 128 + lrow) * 2048 + lhalf * 16;

    for (int k0 = 0; k0 < 2048; k0 += 32) {
        #pragma unroll
        for (int c = 0; c < 4; c++) {
            const float4 va = *reinterpret_cast<const float4*>(ga + k0 + c * 4);
            const float4 vb = *reinterpret_cast<const float4*>(gb + k0 + c * 4);
            ushort4 ua = make_ushort4(f2bf(va.x), f2bf(va.y), f2bf(va.z), f2bf(va.w));
            ushort4 ub = make_ushort4(f2bf(vb.x), f2bf(vb.y), f2bf(vb.z), f2bf(vb.w));
            *reinterpret_cast<ushort4*>(&As[lrow][lhalf * 16 + c * 4]) = ua;
            *reinterpret_cast<ushort4*>(&Bs[lrow][lhalf * 16 + c * 4]) = ub;
        }
        __syncthreads();
        bf16x8 af[4], bfr[4];
        #pragma unroll
        for (int i = 0; i < 4; i++)
            af[i] = *reinterpret_cast<const bf16x8*>(&As[wm * 64 + i * 16 + l15][quad * 8]);
        #pragma unroll
        for (int j = 0; j < 4; j++)
            bfr[j] = *reinterpret_cast<const bf16x8*>(&Bs[wn * 64 + j * 16 + l15][quad * 8]);
        #pragma unroll
        for (int i = 0; i < 4; i++)
            #pragma unroll
            for (int j = 0; j < 4; j++)
                acc[i][j] = __builtin_amdgcn_mfma_f32_16x16x32_bf16(af[i], bfr[j], acc[i][j], 0, 0, 0);
        __syncthreads();
    }

    #pragma unroll
    for (int i = 0; i < 4; i++) {
        #pragma unroll
        for (int r = 0; r < 4; r++) {
            const int row_g = bm * 128 + wm * 64 + i * 16 + quad * 4 + r;
            const int pk01 = __builtin_amdgcn_cvt_pk_fp8_f32(acc[i][0][r], acc[i][1][r], 0, 0);
            const int pk23 = __builtin_amdgcn_cvt_pk_fp8_f32(acc[i][2][r], acc[i][3][r], 0, 0);
            const uchar q8[4] = { (uchar)(pk01 & 0xff), (uchar)((pk01 >> 8) & 0xff),
                                  (uchar)(pk23 & 0xff), (uchar)((pk23 >> 8) & 0xff) };
            #pragma unroll
            for (int j = 0; j < 4; j++) {
                const int col_g = bn * 128 + wn * 64 + j * 16 + l15;
                Z8F[fl_off(row_g, col_g)] = q8[j];
            }
            const float q0 = __builtin_amdgcn_cvt_f32_fp8(pk01, 0);
            const float q1 = __builtin_amdgcn_cvt_f32_fp8(pk01, 1);
            const float q2 = __builtin_amdgcn_cvt_f32_fp8(pk23, 0);
            const float q3 = __builtin_amdgcn_cvt_f32_fp8(pk23, 1);
            float pw = q0 * q0 + q1 * q1 + q2 * q2 + q3 * q3;
            pw += __shfl_xor(pw, 1, 16);
            pw += __shfl_xor(pw, 2, 16);
            pw += __shfl_xor(pw, 4, 16);
            pw += __shfl_xor(pw, 8, 16);
            if (l15 == 0) atomicAdd(&norm2[row_g], pw);
        }
    }
}

// ---------------------------------------------------------------- g2_main
// S = Z8F[:8192g] @ Z8F[8192g:]^T, fp8 16x16x32 MFMA, 128x128 tile,
// streaming (no LDS in K-loop, no barriers) [r7]. Slimmed fused epilogue.
__global__ __launch_bounds__(256, 2) void g2_main(
    const uchar* __restrict__ Z8F, const float* __restrict__ norm2,
    float* __restrict__ rowse, float* __restrict__ bsum, float* __restrict__ bdiag)
{
    __shared__ float lds_red[2][128][18];   // 18 KB (pad 18: 2-way max on store)
    __shared__ float red[8];

    const int bn = blockIdx.x;        // 0..63
    const int bm = blockIdx.y;        // 0..63
    const int t = threadIdx.x;
    const int wave = t >> 6, lane = t & 63;
    const int wm = wave & 1, wn = wave >> 1;       // 64x64 quadrant per wave
    const int quad = lane >> 4, l15 = lane & 15;

    floatx4 acc[4][4];
    #pragma unroll
    for (int i = 0; i < 4; i++)
        #pragma unroll
        for (int j = 0; j < 4; j++) acc[i][j] = {0.f, 0.f, 0.f, 0.f};

    const uchar* baseA = Z8F + ((size_t)(bm * 8 + wm * 4) * 16) * 512 + lane * 8;
    const uchar* baseB = Z8F + ((size_t)(512 + bn * 8 + wn * 4) * 16) * 512 + lane * 8;

    #pragma unroll 4
    for (int c = 0; c < 16; c++) {
        long a[4], b[4];
        #pragma unroll
        for (int i = 0; i < 4; i++) {
            a[i] = *reinterpret_cast<const long*>(baseA + i * 8192 + c * 512);
            b[i] = *reinterpret_cast<const long*>(baseB + i * 8192 + c * 512);
        }
        #pragma unroll
        for (int i = 0; i < 4; i++)
            #pragma unroll
            for (int j = 0; j < 4; j++)
                acc[i][j] = __builtin_amdgcn_mfma_f32_16x16x32_fp8_fp8(a[i], b[j], acc[i][j], 0, 0, 0);
    }

    // Slim epilogue: sim2 = dot * rz * rc * (10*log2e); rowexp via exp2.
    float rc4[4];
    #pragma unroll
    for (int j = 0; j < 4; j++)
        rc4[j] = rsqrtf(fmaxf(norm2[8192 + bn * 128 + wn * 64 + j * 16 + l15], 1e-30f));

    const bool diagblk = (bm == bn) && (wm == wn);
    float s_tot2 = 0.f, s_diag2 = 0.f;
    #pragma unroll
    for (int i = 0; i < 4; i++) {
        #pragma unroll
        for (int r = 0; r < 4; r++) {
            const int row_t = wm * 64 + i * 16 + quad * 4 + r;
            const float rzl2 = rsqrtf(fmaxf(norm2[bm * 128 + row_t], 1e-30f)) * 14.4269504089f;
            float rx = 0.f;
            #pragma unroll
            for (int j = 0; j < 4; j++) {
                const float sim2 = acc[i][j][r] * rzl2 * rc4[j];
                s_tot2 += sim2;
                rx += exp2f(sim2);
            }
            lds_red[wn][row_t][l15] = rx;
            if (diagblk) {
                const float sdv = acc[i][i][r] * rzl2 * rc4[i];
                s_diag2 += (l15 == quad * 4 + r) ? sdv : 0.f;
            }
        }
    }
    __syncthreads();

    // batched row reduction: 256 threads -> 128 rows x 2 col-half partial sums
    {
        const int row_t = t >> 1, part = t & 1;
        float v = 0.f;
        #pragma unroll
        for (int c = 0; c < 16; c++) v += lds_red[part][row_t][c];
        v += __shfl_xor(v, 1, 64);          // combine the two col-halves
        if (part == 0) atomicAdd(&rowse[bm * 128 + row_t], v);
    }

    #pragma unroll
    for (int off = 32; off; off >>= 1) {
        s_tot2  += __shfl_xor(s_tot2, off, 64);
        s_diag2 += __shfl_xor(s_diag2, off, 64);
    }
    if (lane == 0) { red[wave] = s_tot2; red[4 + wave] = s_diag2; }
    __syncthreads();
    if (t == 0) {
        bsum[bm * 64 + bn]  = (red[0] + red[1] + red[2] + red[3]) * 0.69314718056f;
        bdiag[bm * 64 + bn] = (red[4] + red[5] + red[6] + red[7]) * 0.69314718056f;
    }
}

// ---------------------------------------------------------------- finalize
__global__ __launch_bounds__(256) void finalize_kernel(
    const float* __restrict__ rowse, const float* __restrict__ bsum,
    const float* __restrict__ bdiag, float* __restrict__ out)
{
    float a = 0.f, b = 0.f, c = 0.f;
    for (int i = threadIdx.x; i < 8192; i += 256) a += logf(rowse[i]);
    for (int i = threadIdx.x; i < 4096; i += 256) { b += bsum[i]; c += bdiag[i]; }
    #pragma unroll
    for (int off = 32; off; off >>= 1) {
        a += __shfl_xor(a, off, 64);
        b += __shfl_xor(b, off, 64);
        c += __shfl_xor(c, off, 64);
    }
    __shared__ float ra[4], rb[4], rc[4];
    const int wave = threadIdx.x >> 6, lane = threadIdx.x & 63;
    if (lane == 0) { ra[wave] = a; rb[wave] = b; rc[wave] = c; }
    __syncthreads();
    if (threadIdx.x == 0) {
        const float A = ra[0] + ra[1] + ra[2] + ra[3];
        const float B = rb[0] + rb[1] + rb[2] + rb[3];
        const float C = rc[0] + rc[1] + rc[2] + rc[3];
        const float diag_mean = C / 8192.f;
        out[0] = A / 8192.f - diag_mean;            // loss
        out[1] = diag_mean;                         // sim_pos
        out[2] = B / (8192.f * 8192.f);             // sim_mean
    }
}

// ---------------------------------------------------------------- launch
extern "C" void kernel_launch(void* const* d_in, const int* in_sizes, int n_in,
                              void* d_out, int out_size, void* d_ws, size_t ws_size,
                              hipStream_t stream) {
    const float* h = (const float*)d_in[0];   // [16384, 2048]
    const float* W = (const float*)d_in[1];   // [512, 2048]
    float* out = (float*)d_out;               // [3]

    char* ws = (char*)d_ws;
    float* norm2 = (float*)(ws);                            // 16384 f @ 0
    float* rowse = (float*)(ws + 65536);                    //  8192 f
    float* bsum  = (float*)(ws + 98304);                    //  4096 f
    float* bdiag = (float*)(ws + 114688);                   //  4096 f
    uchar* Z8F   = (uchar*)(ws + 131072);                   // frag-layout fp8 (8.39 MB)
    uchar* W8    = (uchar*)(ws + 8519680);                  // 512x2048 fp8 (1 MB)
    uchar* h8    = (uchar*)(ws + 9568256);                  // 16384x2048 fp8 (33.55 MB)
    const size_t NEED_FAST = 43122688ull;                   // ~43.1 MB

    hipMemsetAsync(ws, 0, 131072, stream);    // zero norm2 + rowse (+bsum/bdiag)

    if (ws_size >= NEED_FAST) {
        const int nh = 16384 * 2048, nw = 512 * 2048;
        hipLaunchKernelGGL(cast_fp8_kernel, dim3(nh / 2048), dim3(256), 0, stream, h, h8, nh, 1.0f);
        hipLaunchKernelGGL(cast_fp8_kernel, dim3(nw / 2048), dim3(256), 0, stream, W, W8, nw, 32.0f);
        hipLaunchKernelGGL(g1_main, dim3(4, 128), dim3(256), 0, stream, h8, W8, Z8F, norm2);
    } else {
        hipLaunchKernelGGL(g1_slow, dim3(4, 128), dim3(256), 0, stream, h, W, Z8F, norm2);
    }
    hipLaunchKernelGGL(g2_main, dim3(64, 64), dim3(256), 0, stream, Z8F, norm2, rowse, bsum, bdiag);
    hipLaunchKernelGGL(finalize_kernel, dim3(1), dim3(256), 0, stream, rowse, bsum, bdiag, out);
}